// Round 6
// baseline (539.474 us; speedup 1.0000x reference)
//
#include <hip/hip_runtime.h>
#include <math.h>

#define N_NODES 57344
#define N_EDGES 458752
#define DIM_IN 128
#define DIM_H1 256
#define DIM_H2 64
#define DIM_A 11
#define NB 16
#define MAXB 4096
#define OUT_PER_B (MAXB*DIM_A)   // 45056
#define OUT_SZ (NB*OUT_PER_B)    // 720896
#define NEG_FILL (-1.0e30f)

typedef unsigned short u16;
typedef unsigned int u32;
typedef __bf16 bf16x8 __attribute__((ext_vector_type(8)));
typedef float f32x4 __attribute__((ext_vector_type(4)));

__device__ __forceinline__ float bflo(u32 u){ union{u32 i; float f;} x; x.i = u<<16; return x.f; }
__device__ __forceinline__ float bfhi(u32 u){ union{u32 i; float f;} x; x.i = u & 0xFFFF0000u; return x.f; }
__device__ __forceinline__ u32 f2bf(float f){ union{float f; u32 i;} x; x.f=f; return (x.i + 0x7FFFu + ((x.i>>16)&1u)) >> 16; }

__device__ __forceinline__ float wave_max(float v){
  #pragma unroll
  for (int off=32; off; off>>=1) v = fmaxf(v, __shfl_xor(v, off));
  return v;
}
__device__ __forceinline__ float wave_sum(float v){
  #pragma unroll
  for (int off=32; off; off>>=1) v += __shfl_xor(v, off);
  return v;
}

// ---------------- init
__global__ __launch_bounds__(256) void k_init(int* cnt, int* bid, const int* __restrict__ batches,
                                              float* oacc, float* out){
  int i = blockIdx.x*256 + threadIdx.x;
  if (i < N_NODES){
    cnt[i] = 0;
    int lo=0, hi=NB-1;
    while (lo<hi){ int mid=(lo+hi+1)>>1; if (batches[mid]<=i) lo=mid; else hi=mid-1; }
    bid[i]=lo;
  }
  if (i < 3*NB*256) oacc[i] = 0.0f;
  if (i < OUT_SZ) out[i] = NEG_FILL;
}

__global__ __launch_bounds__(256) void k_deg(const int* __restrict__ ei, int* cnt){
  int e = blockIdx.x*256 + threadIdx.x;
  if (e < N_EDGES) atomicAdd(&cnt[ei[N_EDGES + e]], 1);
}

__global__ __launch_bounds__(256) void k_scanA(const int* __restrict__ cnt, int* bsum){
  __shared__ int s[256];
  int t=threadIdx.x; int i=blockIdx.x*256+t;
  s[t]=cnt[i]; __syncthreads();
  for (int off=128; off; off>>=1){ if (t<off) s[t]+=s[t+off]; __syncthreads(); }
  if (t==0) bsum[blockIdx.x]=s[0];
}
__global__ __launch_bounds__(256) void k_scanB(const int* __restrict__ bsum, int* boff){
  __shared__ int s[256];
  int t=threadIdx.x;
  int v = (t < N_NODES/256) ? bsum[t] : 0;
  s[t]=v; __syncthreads();
  for (int o=1;o<256;o<<=1){
    int a = (t>=o) ? s[t-o] : 0;
    __syncthreads();
    s[t] += a;
    __syncthreads();
  }
  if (t < N_NODES/256) boff[t] = s[t] - v;
}
__global__ __launch_bounds__(256) void k_scanC(const int* __restrict__ cnt, const int* __restrict__ boff,
                                               int* rowstart, int* cursor, float* dis){
  __shared__ int s[256];
  int t=threadIdx.x; int i=blockIdx.x*256+t;
  int v=cnt[i]; s[t]=v; __syncthreads();
  for (int off=1; off<256; off<<=1){
    int add = (t>=off)? s[t-off] : 0;
    __syncthreads();
    s[t]+=add;
    __syncthreads();
  }
  int rs = boff[blockIdx.x] + s[t] - v;
  rowstart[i]=rs; cursor[i]=rs;
  dis[i] = rsqrtf(1.0f + (float)v);
}
__global__ __launch_bounds__(256) void k_place(const int* __restrict__ ei, int* cursor, int* csr_src){
  int e = blockIdx.x*256 + threadIdx.x;
  if (e < N_EDGES){
    int s = ei[e], d = ei[N_EDGES+e];
    int slot = atomicAdd(&cursor[d], 1);
    csr_src[slot] = s;
  }
}

// ---------------- x fp32 -> bf16
__global__ __launch_bounds__(256) void k_cvtx(const float* __restrict__ x, u16* __restrict__ xb){
  int i = blockIdx.x*256 + threadIdx.x;
  float4 v = *(const float4*)(x + (size_t)i*4);
  u32 lo = f2bf(v.x) | (f2bf(v.y)<<16);
  u32 hi = f2bf(v.z) | (f2bf(v.w)<<16);
  *(uint2*)(xb + (size_t)i*4) = make_uint2(lo, hi);
}

// ---------------- weight prep
__global__ __launch_bounds__(256) void k_prep(
    const float* __restrict__ conv1_w, const float* __restrict__ g0_aw, const float* __restrict__ g0_fw,
    const float* __restrict__ g1_aw, const float* __restrict__ g1_fw, const float* __restrict__ conv2_w,
    const float* __restrict__ g2_aw, const float* __restrict__ g2_fw, const float* __restrict__ o1_w,
    const float* __restrict__ g0_ab, const float* __restrict__ g0_fb,
    const float* __restrict__ g1_ab, const float* __restrict__ g1_fb,
    const float* __restrict__ g2_ab, const float* __restrict__ g2_fb,
    u16* conv1T, u16* Wt0, u16* Wt1, u16* conv2T, u16* Wt2, u16* o1T,
    float* cb0, float* cb1, float* cb2){
  int i = blockIdx.x*256 + threadIdx.x;
  if (i < 32768){ int k=i>>8, n=i&255; conv1T[n*128+k]=(u16)f2bf(conv1_w[i]); return; } i-=32768;
  if (i < 32768){ int k=i>>8, n=i&255; Wt0[n*128+k]=(u16)f2bf(g0_aw[i]); return; } i-=32768;
  if (i < 32768){ int k=i>>8, n=i&255; Wt0[(256+n)*128+k]=(u16)f2bf(g0_fw[i]); return; } i-=32768;
  if (i < 65536){ int k=i>>8, n=i&255; Wt1[n*256+k]=(u16)f2bf(g1_aw[i]); return; } i-=65536;
  if (i < 65536){ int k=i>>8, n=i&255; Wt1[(256+n)*256+k]=(u16)f2bf(g1_fw[i]); return; } i-=65536;
  if (i < 16384){ int k=i>>6, n=i&63;  conv2T[n*256+k]=(u16)f2bf(conv2_w[i]); return; } i-=16384;
  if (i < 4096) { int k=i>>6, n=i&63;  Wt2[n*64+k]=(u16)f2bf(g2_aw[i]); return; } i-=4096;
  if (i < 4096) { int k=i>>6, n=i&63;  Wt2[(64+n)*64+k]=(u16)f2bf(g2_fw[i]); return; } i-=4096;
  if (i < 16384){ int k=i>>8, n=i&255; o1T[n*64+k]=(u16)f2bf(o1_w[i]); return; } i-=16384;
  if (i < 256){ cb0[i]=g0_ab[i]; return; } i-=256;
  if (i < 256){ cb0[256+i]=g0_fb[i]; return; } i-=256;
  if (i < 256){ cb1[i]=g1_ab[i]; return; } i-=256;
  if (i < 256){ cb1[256+i]=g1_fb[i]; return; } i-=256;
  if (i < 64) { cb2[i]=g2_ab[i]; return; } i-=64;
  if (i < 64) { cb2[64+i]=g2_fb[i]; return; }
}

// ---------------- GCN1 aggregation, 4x unrolled
__global__ __launch_bounds__(256) void k_agg1b(const u16* __restrict__ xb, const float* __restrict__ dis,
        const int* __restrict__ rowstart, const int* __restrict__ cnt, const int* __restrict__ csr_src,
        u16* __restrict__ agg){
  int d = (blockIdx.x*256 + threadIdx.x) >> 6;
  int lane = threadIdx.x & 63;
  float dd = dis[d];
  u32 u = *(const u32*)(xb + (size_t)d*DIM_IN + lane*2);
  float ax = bflo(u)*dd*dd, ay = bfhi(u)*dd*dd;
  int base = rowstart[d], c = cnt[d];
  int j = 0;
  for (; j+4 <= c; j += 4){
    int s0=csr_src[base+j+0], s1=csr_src[base+j+1], s2=csr_src[base+j+2], s3=csr_src[base+j+3];
    u32 u0=*(const u32*)(xb+(size_t)s0*DIM_IN+lane*2);
    u32 u1=*(const u32*)(xb+(size_t)s1*DIM_IN+lane*2);
    u32 u2=*(const u32*)(xb+(size_t)s2*DIM_IN+lane*2);
    u32 u3=*(const u32*)(xb+(size_t)s3*DIM_IN+lane*2);
    float n0=dis[s0]*dd, n1=dis[s1]*dd, n2=dis[s2]*dd, n3=dis[s3]*dd;
    ax=fmaf(bflo(u0),n0,ax); ay=fmaf(bfhi(u0),n0,ay);
    ax=fmaf(bflo(u1),n1,ax); ay=fmaf(bfhi(u1),n1,ay);
    ax=fmaf(bflo(u2),n2,ax); ay=fmaf(bfhi(u2),n2,ay);
    ax=fmaf(bflo(u3),n3,ax); ay=fmaf(bfhi(u3),n3,ay);
  }
  for (; j<c; ++j){
    int s = csr_src[base+j];
    float nrm = dis[s]*dd;
    u32 us = *(const u32*)(xb + (size_t)s*DIM_IN + lane*2);
    ax = fmaf(bflo(us), nrm, ax);
    ay = fmaf(bfhi(us), nrm, ay);
  }
  *(u32*)(agg + (size_t)d*DIM_IN + lane*2) = f2bf(ax) | (f2bf(ay)<<16);
}

// ---------------- GCN2 aggregation, 4x unrolled
__global__ __launch_bounds__(256) void k_agg2b(const u16* __restrict__ hw, const float* __restrict__ dis,
        const int* __restrict__ rowstart, const int* __restrict__ cnt, const int* __restrict__ csr_src,
        const float* __restrict__ b2, u16* __restrict__ h2){
  int d = (blockIdx.x*256 + threadIdx.x) >> 6;
  int lane = threadIdx.x & 63;
  float dd = dis[d];
  float acc = bflo((u32)hw[(size_t)d*DIM_H2 + lane]) * dd*dd;
  int base = rowstart[d], c = cnt[d];
  int j = 0;
  for (; j+4 <= c; j += 4){
    int s0=csr_src[base+j+0], s1=csr_src[base+j+1], s2=csr_src[base+j+2], s3=csr_src[base+j+3];
    u16 v0=hw[(size_t)s0*DIM_H2+lane], v1=hw[(size_t)s1*DIM_H2+lane];
    u16 v2=hw[(size_t)s2*DIM_H2+lane], v3=hw[(size_t)s3*DIM_H2+lane];
    float n0=dis[s0]*dd, n1=dis[s1]*dd, n2=dis[s2]*dd, n3=dis[s3]*dd;
    acc=fmaf(bflo((u32)v0),n0,acc); acc=fmaf(bflo((u32)v1),n1,acc);
    acc=fmaf(bflo((u32)v2),n2,acc); acc=fmaf(bflo((u32)v3),n3,acc);
  }
  for (; j<c; ++j){
    int s = csr_src[base+j];
    acc = fmaf(bflo((u32)hw[(size_t)s*DIM_H2 + lane]), dis[s]*dd, acc);
  }
  h2[(size_t)d*DIM_H2 + lane] = (u16)f2bf(fmaxf(acc + b2[lane], 0.0f));
}

// ---------------- bf16 MFMA GEMM (conv1 / conv2 / head1)
__global__ __launch_bounds__(256) void k_mm(const u16* __restrict__ A, const u16* __restrict__ Wt,
        const float* __restrict__ bias, const float* __restrict__ rowbias, const int* __restrict__ bid,
        u16* __restrict__ C, int K, int Ncol, int flags){
  __shared__ u16 As[128][40];
  __shared__ u16 Bs[64][40];
  const int t = threadIdx.x;
  const int row0 = blockIdx.x*128, col0 = blockIdx.y*64;
  const int lane = t & 63, w = t >> 6;
  const int lr = lane & 15, q = lane >> 4;
  f32x4 acc[2][4];
  #pragma unroll
  for (int r=0;r<2;++r){
    #pragma unroll
    for (int c=0;c<4;++c){ f32x4 z = {}; acc[r][c] = z; }
  }
  for (int k0=0; k0<K; k0+=32){
    #pragma unroll
    for (int i=0;i<2;++i){
      int ch = t + i*256;
      int r = ch>>2, ko = (ch&3)*8;
      *(uint4*)(&As[r][ko]) = *(const uint4*)(A + (size_t)(row0+r)*K + k0 + ko);
    }
    {
      int r = t>>2, ko = (t&3)*8;
      *(uint4*)(&Bs[r][ko]) = *(const uint4*)(Wt + (size_t)(col0+r)*K + k0 + ko);
    }
    __syncthreads();
    bf16x8 af0 = *(const bf16x8*)(&As[w*32 + lr][q*8]);
    bf16x8 af1 = *(const bf16x8*)(&As[w*32 + 16 + lr][q*8]);
    #pragma unroll
    for (int c=0;c<4;++c){
      bf16x8 bfr = *(const bf16x8*)(&Bs[c*16 + lr][q*8]);
      acc[0][c] = __builtin_amdgcn_mfma_f32_16x16x32_bf16(af0, bfr, acc[0][c], 0,0,0);
      acc[1][c] = __builtin_amdgcn_mfma_f32_16x16x32_bf16(af1, bfr, acc[1][c], 0,0,0);
    }
    __syncthreads();
  }
  float bcol[4];
  #pragma unroll
  for (int c=0;c<4;++c){
    int col = col0 + c*16 + lr;
    float bv = 0.f;
    if (flags & 4) bv += bias[col];
    if (flags & 2) bv += rowbias[(size_t)bid[row0]*Ncol + col];
    bcol[c] = bv;
  }
  #pragma unroll
  for (int r=0;r<2;++r){
    #pragma unroll
    for (int c=0;c<4;++c){
      int col = col0 + c*16 + lr;
      #pragma unroll
      for (int i=0;i<4;++i){
        int row = row0 + w*32 + r*16 + q*4 + i;
        float v = acc[r][c][i] + bcol[c];
        if (flags & 1) v = fmaxf(v, 0.f);
        C[(size_t)row*Ncol + col] = (u16)f2bf(v);
      }
    }
  }
}

// ---------------- fused attention v2 (H=256): wave-specialized, register-resident softmax.
// Block = 32 nodes, 256 threads. Waves 0-1: S for rows [w*16,16); waves 2-3: F for same rows.
// Only p crosses waves via LDS. Wt = [2H][Din], cb = [ab|fb].
template<int DIN>
__global__ __launch_bounds__(256) void k_attnf2(const u16* __restrict__ V, const u16* __restrict__ Wt,
        const float* __restrict__ cb, const int* __restrict__ bid, float* __restrict__ o){
  constexpr int H = 256;
  constexpr int KS = DIN/32;
  constexpr int AST = DIN + 8;
  constexpr int PST = H + 8;
  __shared__ u16 As[32*AST];
  __shared__ u16 Psh[32*PST];
  const int t = threadIdx.x;
  const int node0 = blockIdx.x*32;     // 32 | 2048 -> single batch
  const int lane = t & 63, w = t >> 6;
  const int lr = lane & 15, q = lane >> 4;
  const bool isS = (w < 2);
  const int rw = w & 1;                // row-group: rows rw*16 .. rw*16+15
  // stage A (32 x DIN)
  #pragma unroll
  for (int i = 0; i < (32*DIN/8)/256; ++i){
    int ch = t + i*256;
    int r = ch / (DIN/8), co = (ch % (DIN/8))*8;
    *(uint4*)(&As[r*AST + co]) = *(const uint4*)(V + (size_t)(node0+r)*DIN + co);
  }
  __syncthreads();
  // GEMM: 16 rows x 256 cols per wave, B from global (L2-resident weights)
  f32x4 acc[16];
  #pragma unroll
  for (int c=0;c<16;++c){ f32x4 z = {}; acc[c] = z; }
  const u16* Wbase = Wt + (size_t)(isS ? 0 : H)*DIN;
  #pragma unroll
  for (int k=0;k<KS;++k){
    bf16x8 a = *(const bf16x8*)(&As[(rw*16 + lr)*AST + k*32 + q*8]);
    #pragma unroll
    for (int c=0;c<16;++c){
      bf16x8 b = *(const bf16x8*)(Wbase + (size_t)(c*16 + lr)*DIN + k*32 + q*8);
      acc[c] = __builtin_amdgcn_mfma_f32_16x16x32_bf16(a, b, acc[c], 0,0,0);
    }
  }
  // + bias (C-layout: col = c*16+lr, row = q*4+i within the 16-row group)
  #pragma unroll
  for (int c=0;c<16;++c){
    float bv = cb[(isS ? 0 : H) + c*16 + lr];
    #pragma unroll
    for (int i=0;i<4;++i) acc[c][i] += bv;
  }
  if (isS){
    // in-register softmax over 256 cols for rows q*4+i (reduce over 16 frags + 16 lr lanes)
    float m[4], iz[4];
    #pragma unroll
    for (int i=0;i<4;++i){
      float mx = acc[0][i];
      #pragma unroll
      for (int c=1;c<16;++c) mx = fmaxf(mx, acc[c][i]);
      #pragma unroll
      for (int off=1; off<16; off<<=1) mx = fmaxf(mx, __shfl_xor(mx, off));
      m[i] = mx;
    }
    #pragma unroll
    for (int i=0;i<4;++i){
      float s = 0.f;
      #pragma unroll
      for (int c=0;c<16;++c) s += __expf(acc[c][i] - m[i]);
      #pragma unroll
      for (int off=1; off<16; off<<=1) s += __shfl_xor(s, off);
      iz[i] = 1.0f/s;
    }
    #pragma unroll
    for (int c=0;c<16;++c){
      #pragma unroll
      for (int i=0;i<4;++i){
        Psh[(rw*16 + q*4 + i)*PST + c*16 + lr] = (u16)f2bf(__expf(acc[c][i]-m[i])*iz[i]);
      }
    }
  }
  __syncthreads();
  if (!isS){
    const int b = bid[node0];
    #pragma unroll
    for (int c=0;c<16;++c){
      float cs = 0.f;
      #pragma unroll
      for (int i=0;i<4;++i){
        float p = bflo((u32)Psh[(rw*16 + q*4 + i)*PST + c*16 + lr]);
        cs = fmaf(p, acc[c][i], cs);
      }
      cs += __shfl_xor(cs, 16);
      cs += __shfl_xor(cs, 32);            // sum over q (16 rows)
      if (q == (c & 3)) atomicAdd(&o[b*H + c*16 + lr], cs);
    }
  }
}

// ---------------- fused attention (H=64 small layer, original structure)
template<int DIN, int H>
__global__ __launch_bounds__(256) void k_attnf(const u16* __restrict__ V, const u16* __restrict__ Wt,
        const float* __restrict__ cb, const int* __restrict__ bid, float* __restrict__ o){
  constexpr int CF  = H/64;
  constexpr int KS  = DIN/32;
  constexpr int AST = DIN + 8;
  constexpr int SST = H + 4;
  __shared__ u16 As[32*AST];
  __shared__ u16 Ssh[32*SST];
  __shared__ u16 Fsh[32*SST];
  __shared__ float mZ[2][32];
  const int t = threadIdx.x;
  const int node0 = blockIdx.x*32;
  const int lane = t & 63, w = t >> 6;
  const int lr = lane & 15, q = lane >> 4;
  #pragma unroll
  for (int i = 0; i < (32*DIN/8)/256; ++i){
    int ch = t + i*256;
    int r = ch / (DIN/8), co = (ch % (DIN/8))*8;
    *(uint4*)(&As[r*AST + co]) = *(const uint4*)(V + (size_t)(node0+r)*DIN + co);
  }
  __syncthreads();
  #pragma unroll
  for (int ph = 0; ph < 2; ++ph){
    f32x4 acc[2][CF];
    #pragma unroll
    for (int r=0;r<2;++r){
      #pragma unroll
      for (int c=0;c<CF;++c){ f32x4 z = {}; acc[r][c] = z; }
    }
    #pragma unroll
    for (int k=0;k<KS;++k){
      bf16x8 a0 = *(const bf16x8*)(&As[lr*AST + k*32 + q*8]);
      bf16x8 a1 = *(const bf16x8*)(&As[(16+lr)*AST + k*32 + q*8]);
      #pragma unroll
      for (int c=0;c<CF;++c){
        int col = ph*H + w*(16*CF) + c*16 + lr;
        bf16x8 b = *(const bf16x8*)(Wt + (size_t)col*DIN + k*32 + q*8);
        acc[0][c] = __builtin_amdgcn_mfma_f32_16x16x32_bf16(a0, b, acc[0][c], 0,0,0);
        acc[1][c] = __builtin_amdgcn_mfma_f32_16x16x32_bf16(a1, b, acc[1][c], 0,0,0);
      }
    }
    u16* dst = ph ? Fsh : Ssh;
    #pragma unroll
    for (int c=0;c<CF;++c){
      int colL = w*(16*CF) + c*16 + lr;
      float bias = cb[ph*H + colL];
      #pragma unroll
      for (int rf=0; rf<2; ++rf){
        #pragma unroll
        for (int i=0;i<4;++i){
          int row = rf*16 + q*4 + i;
          dst[row*SST + colL] = (u16)f2bf(acc[rf][c][i] + bias);
        }
      }
    }
    if (ph==0){
      __syncthreads();
      #pragma unroll
      for (int nn=0; nn<8; ++nn){
        int n = w*8 + nn;
        constexpr int VPL = H/64;
        float vals[VPL]; float mx = -1e30f;
        if constexpr (VPL == 4){
          uint2 uv = *(const uint2*)(&Ssh[n*SST + lane*4]);
          vals[0]=bflo(uv.x); vals[1]=bfhi(uv.x); vals[2]=bflo(uv.y); vals[3]=bfhi(uv.y);
          mx = fmaxf(fmaxf(vals[0],vals[1]), fmaxf(vals[2],vals[3]));
        } else {
          vals[0] = bflo((u32)Ssh[n*SST + lane]);
          mx = vals[0];
        }
        mx = wave_max(mx);
        float z = 0.f;
        #pragma unroll
        for (int i=0;i<VPL;++i) z += __expf(vals[i]-mx);
        z = wave_sum(z);
        if (lane==0){ mZ[0][n]=mx; mZ[1][n]=1.0f/z; }
      }
    }
  }
  __syncthreads();
  const int col = t % H;
  constexpr int NPER = 32*H/256;
  const int n0 = (t / H) * NPER;
  float acc2 = 0.f;
  #pragma unroll 8
  for (int n=n0; n<n0+NPER; ++n){
    float s = bflo((u32)Ssh[n*SST + col]);
    float f = bflo((u32)Fsh[n*SST + col]);
    acc2 = fmaf(__expf(s - mZ[0][n]) * mZ[1][n], f, acc2);
  }
  atomicAdd(&o[bid[node0]*H + col], acc2);
}

// ---------------- g update, parallel-K
template<int H, bool HASG>
__global__ __launch_bounds__(256) void k_gup2(const float* __restrict__ o, const float* __restrict__ gprev,
        const float* __restrict__ gw, const float* __restrict__ gb, float* __restrict__ gout){
  constexpr int KT = H + (HASG ? 256 : 0);
  constexpr int KPS = KT/8;
  __shared__ float vsh[KT];
  __shared__ float red[8][33];
  const int b = blockIdx.x;
  const int c = threadIdx.x & 31;
  const int s = threadIdx.x >> 5;
  const int col = blockIdx.y*32 + c;
  for (int k=threadIdx.x; k<KT; k+=256)
    vsh[k] = (k < H) ? o[b*H + k] : gprev[b*256 + (k - H)];
  __syncthreads();
  float acc = 0.f;
  const float* wp = gw + (size_t)(s*KPS)*256 + col;
  #pragma unroll 8
  for (int i=0;i<KPS;++i)
    acc = fmaf(vsh[s*KPS+i], wp[(size_t)i*256], acc);
  red[s][c] = acc;
  __syncthreads();
  if (s==0){
    float sum = 0.f;
    #pragma unroll
    for (int j=0;j<8;++j) sum += red[j][c];
    float gp = HASG ? gprev[b*256+col] : 0.f;
    gout[b*256+col] = gp + sum + gb[col];
  }
}

// ---------------- per-batch head bias, parallel-K
__global__ __launch_bounds__(256) void k_hb2(const float* __restrict__ g2, const float* __restrict__ o1w,
                                             const float* __restrict__ o1b, float* __restrict__ hb){
  __shared__ float vsh[256];
  __shared__ float red[8][33];
  const int b = blockIdx.x;
  const int c = threadIdx.x & 31;
  const int s = threadIdx.x >> 5;
  const int col = blockIdx.y*32 + c;
  vsh[threadIdx.x] = g2[b*256 + threadIdx.x];
  __syncthreads();
  float acc = 0.f;
  const float* wp = o1w + (size_t)(64 + s*32)*256 + col;
  #pragma unroll 8
  for (int i=0;i<32;++i)
    acc = fmaf(vsh[s*32+i], wp[(size_t)i*256], acc);
  red[s][c] = acc;
  __syncthreads();
  if (s==0){
    float sum = 0.f;
    #pragma unroll
    for (int j=0;j<8;++j) sum += red[j][c];
    hb[b*256+col] = sum + o1b[col];
  }
}

// ---------------- head layer 2 + pack
__global__ __launch_bounds__(256) void k_head2(const u16* __restrict__ z, const float* __restrict__ w,
        const float* __restrict__ bvec, const int* __restrict__ bid, const int* __restrict__ batches,
        float* __restrict__ out){
  __shared__ float zs[16][257];
  int t = threadIdx.x;
  int g0 = blockIdx.x*16;
  #pragma unroll
  for (int i=0;i<2;++i){
    int ch = t + i*256;
    int v = ch>>5, ko=(ch&31)*8;
    uint4 qv = *(const uint4*)(z + (size_t)(g0+v)*256 + ko);
    zs[v][ko+0]=bflo(qv.x); zs[v][ko+1]=bfhi(qv.x);
    zs[v][ko+2]=bflo(qv.y); zs[v][ko+3]=bfhi(qv.y);
    zs[v][ko+4]=bflo(qv.z); zs[v][ko+5]=bfhi(qv.z);
    zs[v][ko+6]=bflo(qv.w); zs[v][ko+7]=bfhi(qv.w);
  }
  __syncthreads();
  int v = t >> 4, c = t & 15;
  if (c < DIM_A){
    float acc = bvec[c];
    for (int k=0;k<256;++k) acc = fmaf(zs[v][k], w[k*DIM_A + c], acc);
    int node = g0 + v;
    int bb = bid[node];
    out[(size_t)bb*OUT_PER_B + (size_t)(node - batches[bb])*DIM_A + c] = acc;
  }
}

extern "C" void kernel_launch(void* const* d_in, const int* in_sizes, int n_in,
                              void* d_out, int out_size, void* d_ws, size_t ws_size,
                              hipStream_t stream){
  const float* x       = (const float*)d_in[0];
  const int*   ei      = (const int*)d_in[1];
  const int*   batches = (const int*)d_in[2];
  const float* conv1_w = (const float*)d_in[4];
  const float* conv1_b = (const float*)d_in[5];
  const float* conv2_w = (const float*)d_in[6];
  const float* conv2_b = (const float*)d_in[7];
  const float* g0_aw = (const float*)d_in[8];  const float* g0_ab = (const float*)d_in[9];
  const float* g0_fw = (const float*)d_in[10]; const float* g0_fb = (const float*)d_in[11];
  const float* g0_gw = (const float*)d_in[12]; const float* g0_gb = (const float*)d_in[13];
  const float* g1_aw = (const float*)d_in[14]; const float* g1_ab = (const float*)d_in[15];
  const float* g1_fw = (const float*)d_in[16]; const float* g1_fb = (const float*)d_in[17];
  const float* g1_gw = (const float*)d_in[18]; const float* g1_gb = (const float*)d_in[19];
  const float* g2_aw = (const float*)d_in[20]; const float* g2_ab = (const float*)d_in[21];
  const float* g2_fw = (const float*)d_in[22]; const float* g2_fb = (const float*)d_in[23];
  const float* g2_gw = (const float*)d_in[24]; const float* g2_gb = (const float*)d_in[25];
  const float* o1_w  = (const float*)d_in[26]; const float* o1_b  = (const float*)d_in[27];
  const float* o2_w  = (const float*)d_in[28]; const float* o2_b  = (const float*)d_in[29];
  float* out = (float*)d_out;

  char* W = (char*)d_ws;
  size_t off = 0;
  auto alloc = [&](size_t bytes)->void*{
    off = (off + 255) & ~(size_t)255;
    void* p = W + off; off += bytes; return p;
  };
  float* dis      = (float*)alloc(N_NODES*4);
  int*   cnt      = (int*)  alloc(N_NODES*4);
  int*   bid      = (int*)  alloc(N_NODES*4);
  int*   rowstart = (int*)  alloc(N_NODES*4);
  int*   cursor   = (int*)  alloc(N_NODES*4);
  int*   csr_src  = (int*)  alloc(N_EDGES*4);
  int*   bsum     = (int*)  alloc(256*4);
  int*   boff     = (int*)  alloc(256*4);
  float* o0       = (float*)alloc(NB*256*4);
  float* o1a      = (float*)alloc(NB*256*4);
  float* o2a      = (float*)alloc(NB*256*4);
  float* gv0      = (float*)alloc(NB*256*4);
  float* gv1      = (float*)alloc(NB*256*4);
  float* gv2      = (float*)alloc(NB*256*4);
  float* hb       = (float*)alloc(NB*256*4);
  float* cb0      = (float*)alloc(512*4);
  float* cb1      = (float*)alloc(512*4);
  float* cb2      = (float*)alloc(128*4);
  u16* conv1T = (u16*)alloc(32768*2);
  u16* Wt0    = (u16*)alloc(65536*2);
  u16* Wt1    = (u16*)alloc(131072*2);
  u16* conv2T = (u16*)alloc(16384*2);
  u16* Wt2    = (u16*)alloc(8192*2);
  u16* o1T    = (u16*)alloc(16384*2);
  u16* h1b    = (u16*)alloc((size_t)N_NODES*DIM_H1*2);   // 29.4 MB; reused as z
  u16* X      = (u16*)alloc((size_t)N_NODES*DIM_IN*2);   // 14.7 MB: xb; later hw2b | h2b
  u16* agg1b  = (u16*)alloc((size_t)N_NODES*DIM_IN*2);   // 14.7 MB
  u16* xb    = X;
  u16* hw2b  = X;
  u16* h2b   = X + (size_t)N_NODES*DIM_H2;
  u16* z     = h1b;

  // ---- init + CSR ----
  k_init <<<OUT_SZ/256, 256, 0, stream>>>(cnt, bid, batches, o0, out);
  k_deg  <<<N_EDGES/256, 256, 0, stream>>>(ei, cnt);
  k_scanA<<<N_NODES/256, 256, 0, stream>>>(cnt, bsum);
  k_scanB<<<1, 256, 0, stream>>>(bsum, boff);
  k_scanC<<<N_NODES/256, 256, 0, stream>>>(cnt, boff, rowstart, cursor, dis);
  k_place<<<N_EDGES/256, 256, 0, stream>>>(ei, cursor, csr_src);

  // ---- conversions / weight prep ----
  k_cvtx <<<N_NODES*DIM_IN/4/256, 256, 0, stream>>>(x, xb);
  k_prep <<<(270336+1152+255)/256, 256, 0, stream>>>(conv1_w, g0_aw, g0_fw, g1_aw, g1_fw, conv2_w,
            g2_aw, g2_fw, o1_w, g0_ab, g0_fb, g1_ab, g1_fb, g2_ab, g2_fb,
            conv1T, Wt0, Wt1, conv2T, Wt2, o1T, cb0, cb1, cb2);

  // ---- GCN1: aggregate then GEMM(+bias,relu) ----
  k_agg1b<<<N_NODES/4, 256, 0, stream>>>(xb, dis, rowstart, cnt, csr_src, agg1b);
  k_mm   <<<dim3(N_NODES/128, 4), 256, 0, stream>>>(agg1b, conv1T, conv1_b, nullptr, nullptr,
                                                    h1b, DIM_IN, DIM_H1, 4|1);
  // ---- fused attention 0 on xb ----
  k_attnf2<128><<<N_NODES/32, 256, 0, stream>>>(xb, Wt0, cb0, bid, o0);
  k_gup2<256,false><<<dim3(NB,8), 256, 0, stream>>>(o0, nullptr, g0_gw, g0_gb, gv0);

  // ---- fused attention 1 on h1b ----
  k_attnf2<256><<<N_NODES/32, 256, 0, stream>>>(h1b, Wt1, cb1, bid, o1a);
  k_gup2<256,true><<<dim3(NB,8), 256, 0, stream>>>(o1a, gv0, g1_gw, g1_gb, gv1);

  // ---- GCN2: GEMM then aggregate(+bias,relu) ----
  k_mm   <<<dim3(N_NODES/128, 1), 256, 0, stream>>>(h1b, conv2T, nullptr, nullptr, nullptr,
                                                    hw2b, DIM_H1, DIM_H2, 0);
  k_agg2b<<<N_NODES/4, 256, 0, stream>>>(hw2b, dis, rowstart, cnt, csr_src, conv2_b, h2b);

  // ---- fused attention 2 on h2b ----
  k_attnf<64,64><<<N_NODES/32, 256, 0, stream>>>(h2b, Wt2, cb2, bid, o2a);
  k_gup2<64,true><<<dim3(NB,8), 256, 0, stream>>>(o2a, gv1, g2_gw, g2_gb, gv2);

  // ---- head ----
  k_hb2  <<<dim3(NB,8), 256, 0, stream>>>(gv2, o1_w, o1_b, hb);
  k_mm   <<<dim3(N_NODES/128, 4), 256, 0, stream>>>(h2b, o1T, nullptr, hb, bid, z, DIM_H2, 256, 2|1);
  k_head2<<<N_NODES/16, 256, 0, stream>>>(z, o2_w, o2_b, bid, batches, out);

  (void)in_sizes; (void)n_in; (void)out_size; (void)ws_size;
}

// Round 7
// 440.158 us; speedup vs baseline: 1.2256x; 1.2256x over previous
//
#include <hip/hip_runtime.h>
#include <math.h>

#define N_NODES 57344
#define N_EDGES 458752
#define DIM_IN 128
#define DIM_H1 256
#define DIM_H2 64
#define DIM_A 11
#define NB 16
#define MAXB 4096
#define OUT_PER_B (MAXB*DIM_A)   // 45056
#define OUT_SZ (NB*OUT_PER_B)    // 720896
#define NEG_FILL (-1.0e30f)

typedef unsigned short u16;
typedef unsigned int u32;
typedef __bf16 bf16x8 __attribute__((ext_vector_type(8)));
typedef float f32x4 __attribute__((ext_vector_type(4)));

__device__ __forceinline__ float bflo(u32 u){ union{u32 i; float f;} x; x.i = u<<16; return x.f; }
__device__ __forceinline__ float bfhi(u32 u){ union{u32 i; float f;} x; x.i = u & 0xFFFF0000u; return x.f; }
__device__ __forceinline__ u32 f2bf(float f){ union{float f; u32 i;} x; x.f=f; return (x.i + 0x7FFFu + ((x.i>>16)&1u)) >> 16; }

__device__ __forceinline__ float wave_max(float v){
  #pragma unroll
  for (int off=32; off; off>>=1) v = fmaxf(v, __shfl_xor(v, off));
  return v;
}
__device__ __forceinline__ float wave_sum(float v){
  #pragma unroll
  for (int off=32; off; off>>=1) v += __shfl_xor(v, off);
  return v;
}

// ---------------- init
__global__ __launch_bounds__(256) void k_init(int* cnt, int* bid, const int* __restrict__ batches,
                                              float* oacc, float* out){
  int i = blockIdx.x*256 + threadIdx.x;
  if (i < N_NODES){
    cnt[i] = 0;
    int lo=0, hi=NB-1;
    while (lo<hi){ int mid=(lo+hi+1)>>1; if (batches[mid]<=i) lo=mid; else hi=mid-1; }
    bid[i]=lo;
  }
  if (i < 3*NB*256) oacc[i] = 0.0f;
  if (i < OUT_SZ) out[i] = NEG_FILL;
}

__global__ __launch_bounds__(256) void k_deg(const int* __restrict__ ei, int* cnt){
  int e = blockIdx.x*256 + threadIdx.x;
  if (e < N_EDGES) atomicAdd(&cnt[ei[N_EDGES + e]], 1);
}

__global__ __launch_bounds__(256) void k_scanA(const int* __restrict__ cnt, int* bsum){
  __shared__ int s[256];
  int t=threadIdx.x; int i=blockIdx.x*256+t;
  s[t]=cnt[i]; __syncthreads();
  for (int off=128; off; off>>=1){ if (t<off) s[t]+=s[t+off]; __syncthreads(); }
  if (t==0) bsum[blockIdx.x]=s[0];
}
__global__ __launch_bounds__(256) void k_scanB(const int* __restrict__ bsum, int* boff){
  __shared__ int s[256];
  int t=threadIdx.x;
  int v = (t < N_NODES/256) ? bsum[t] : 0;
  s[t]=v; __syncthreads();
  for (int o=1;o<256;o<<=1){
    int a = (t>=o) ? s[t-o] : 0;
    __syncthreads();
    s[t] += a;
    __syncthreads();
  }
  if (t < N_NODES/256) boff[t] = s[t] - v;
}
__global__ __launch_bounds__(256) void k_scanC(const int* __restrict__ cnt, const int* __restrict__ boff,
                                               int* rowstart, int* cursor, float* dis){
  __shared__ int s[256];
  int t=threadIdx.x; int i=blockIdx.x*256+t;
  int v=cnt[i]; s[t]=v; __syncthreads();
  for (int off=1; off<256; off<<=1){
    int add = (t>=off)? s[t-off] : 0;
    __syncthreads();
    s[t]+=add;
    __syncthreads();
  }
  int rs = boff[blockIdx.x] + s[t] - v;
  rowstart[i]=rs; cursor[i]=rs;
  dis[i] = rsqrtf(1.0f + (float)v);
}
__global__ __launch_bounds__(256) void k_place(const int* __restrict__ ei, int* cursor, int* csr_src){
  int e = blockIdx.x*256 + threadIdx.x;
  if (e < N_EDGES){
    int s = ei[e], d = ei[N_EDGES+e];
    int slot = atomicAdd(&cursor[d], 1);
    csr_src[slot] = s;
  }
}

// ---------------- x fp32 -> bf16
__global__ __launch_bounds__(256) void k_cvtx(const float* __restrict__ x, u16* __restrict__ xb){
  int i = blockIdx.x*256 + threadIdx.x;
  float4 v = *(const float4*)(x + (size_t)i*4);
  u32 lo = f2bf(v.x) | (f2bf(v.y)<<16);
  u32 hi = f2bf(v.z) | (f2bf(v.w)<<16);
  *(uint2*)(xb + (size_t)i*4) = make_uint2(lo, hi);
}

// ---------------- weight prep
__global__ __launch_bounds__(256) void k_prep(
    const float* __restrict__ conv1_w, const float* __restrict__ g0_aw, const float* __restrict__ g0_fw,
    const float* __restrict__ g1_aw, const float* __restrict__ g1_fw, const float* __restrict__ conv2_w,
    const float* __restrict__ g2_aw, const float* __restrict__ g2_fw, const float* __restrict__ o1_w,
    const float* __restrict__ g0_ab, const float* __restrict__ g0_fb,
    const float* __restrict__ g1_ab, const float* __restrict__ g1_fb,
    const float* __restrict__ g2_ab, const float* __restrict__ g2_fb,
    u16* conv1T, u16* Wt0, u16* Wt1, u16* conv2T, u16* Wt2, u16* o1T,
    float* cb0, float* cb1, float* cb2){
  int i = blockIdx.x*256 + threadIdx.x;
  if (i < 32768){ int k=i>>8, n=i&255; conv1T[n*128+k]=(u16)f2bf(conv1_w[i]); return; } i-=32768;
  if (i < 32768){ int k=i>>8, n=i&255; Wt0[n*128+k]=(u16)f2bf(g0_aw[i]); return; } i-=32768;
  if (i < 32768){ int k=i>>8, n=i&255; Wt0[(256+n)*128+k]=(u16)f2bf(g0_fw[i]); return; } i-=32768;
  if (i < 65536){ int k=i>>8, n=i&255; Wt1[n*256+k]=(u16)f2bf(g1_aw[i]); return; } i-=65536;
  if (i < 65536){ int k=i>>8, n=i&255; Wt1[(256+n)*256+k]=(u16)f2bf(g1_fw[i]); return; } i-=65536;
  if (i < 16384){ int k=i>>6, n=i&63;  conv2T[n*256+k]=(u16)f2bf(conv2_w[i]); return; } i-=16384;
  if (i < 4096) { int k=i>>6, n=i&63;  Wt2[n*64+k]=(u16)f2bf(g2_aw[i]); return; } i-=4096;
  if (i < 4096) { int k=i>>6, n=i&63;  Wt2[(64+n)*64+k]=(u16)f2bf(g2_fw[i]); return; } i-=4096;
  if (i < 16384){ int k=i>>8, n=i&255; o1T[n*64+k]=(u16)f2bf(o1_w[i]); return; } i-=16384;
  if (i < 256){ cb0[i]=g0_ab[i]; return; } i-=256;
  if (i < 256){ cb0[256+i]=g0_fb[i]; return; } i-=256;
  if (i < 256){ cb1[i]=g1_ab[i]; return; } i-=256;
  if (i < 256){ cb1[256+i]=g1_fb[i]; return; } i-=256;
  if (i < 64) { cb2[i]=g2_ab[i]; return; } i-=64;
  if (i < 64) { cb2[64+i]=g2_fb[i]; return; }
}

// ---------------- GCN1 aggregation, 4x unrolled
__global__ __launch_bounds__(256) void k_agg1b(const u16* __restrict__ xb, const float* __restrict__ dis,
        const int* __restrict__ rowstart, const int* __restrict__ cnt, const int* __restrict__ csr_src,
        u16* __restrict__ agg){
  int d = (blockIdx.x*256 + threadIdx.x) >> 6;
  int lane = threadIdx.x & 63;
  float dd = dis[d];
  u32 u = *(const u32*)(xb + (size_t)d*DIM_IN + lane*2);
  float ax = bflo(u)*dd*dd, ay = bfhi(u)*dd*dd;
  int base = rowstart[d], c = cnt[d];
  int j = 0;
  for (; j+4 <= c; j += 4){
    int s0=csr_src[base+j+0], s1=csr_src[base+j+1], s2=csr_src[base+j+2], s3=csr_src[base+j+3];
    u32 u0=*(const u32*)(xb+(size_t)s0*DIM_IN+lane*2);
    u32 u1=*(const u32*)(xb+(size_t)s1*DIM_IN+lane*2);
    u32 u2=*(const u32*)(xb+(size_t)s2*DIM_IN+lane*2);
    u32 u3=*(const u32*)(xb+(size_t)s3*DIM_IN+lane*2);
    float n0=dis[s0]*dd, n1=dis[s1]*dd, n2=dis[s2]*dd, n3=dis[s3]*dd;
    ax=fmaf(bflo(u0),n0,ax); ay=fmaf(bfhi(u0),n0,ay);
    ax=fmaf(bflo(u1),n1,ax); ay=fmaf(bfhi(u1),n1,ay);
    ax=fmaf(bflo(u2),n2,ax); ay=fmaf(bfhi(u2),n2,ay);
    ax=fmaf(bflo(u3),n3,ax); ay=fmaf(bfhi(u3),n3,ay);
  }
  for (; j<c; ++j){
    int s = csr_src[base+j];
    float nrm = dis[s]*dd;
    u32 us = *(const u32*)(xb + (size_t)s*DIM_IN + lane*2);
    ax = fmaf(bflo(us), nrm, ax);
    ay = fmaf(bfhi(us), nrm, ay);
  }
  *(u32*)(agg + (size_t)d*DIM_IN + lane*2) = f2bf(ax) | (f2bf(ay)<<16);
}

// ---------------- GCN2 aggregation, 4x unrolled
__global__ __launch_bounds__(256) void k_agg2b(const u16* __restrict__ hw, const float* __restrict__ dis,
        const int* __restrict__ rowstart, const int* __restrict__ cnt, const int* __restrict__ csr_src,
        const float* __restrict__ b2, u16* __restrict__ h2){
  int d = (blockIdx.x*256 + threadIdx.x) >> 6;
  int lane = threadIdx.x & 63;
  float dd = dis[d];
  float acc = bflo((u32)hw[(size_t)d*DIM_H2 + lane]) * dd*dd;
  int base = rowstart[d], c = cnt[d];
  int j = 0;
  for (; j+4 <= c; j += 4){
    int s0=csr_src[base+j+0], s1=csr_src[base+j+1], s2=csr_src[base+j+2], s3=csr_src[base+j+3];
    u16 v0=hw[(size_t)s0*DIM_H2+lane], v1=hw[(size_t)s1*DIM_H2+lane];
    u16 v2=hw[(size_t)s2*DIM_H2+lane], v3=hw[(size_t)s3*DIM_H2+lane];
    float n0=dis[s0]*dd, n1=dis[s1]*dd, n2=dis[s2]*dd, n3=dis[s3]*dd;
    acc=fmaf(bflo((u32)v0),n0,acc); acc=fmaf(bflo((u32)v1),n1,acc);
    acc=fmaf(bflo((u32)v2),n2,acc); acc=fmaf(bflo((u32)v3),n3,acc);
  }
  for (; j<c; ++j){
    int s = csr_src[base+j];
    acc = fmaf(bflo((u32)hw[(size_t)s*DIM_H2 + lane]), dis[s]*dd, acc);
  }
  h2[(size_t)d*DIM_H2 + lane] = (u16)f2bf(fmaxf(acc + b2[lane], 0.0f));
}

// ---------------- bf16 MFMA GEMM (conv1 / conv2 / head1)
__global__ __launch_bounds__(256) void k_mm(const u16* __restrict__ A, const u16* __restrict__ Wt,
        const float* __restrict__ bias, const float* __restrict__ rowbias, const int* __restrict__ bid,
        u16* __restrict__ C, int K, int Ncol, int flags){
  __shared__ u16 As[128][40];
  __shared__ u16 Bs[64][40];
  const int t = threadIdx.x;
  const int row0 = blockIdx.x*128, col0 = blockIdx.y*64;
  const int lane = t & 63, w = t >> 6;
  const int lr = lane & 15, q = lane >> 4;
  f32x4 acc[2][4];
  #pragma unroll
  for (int r=0;r<2;++r){
    #pragma unroll
    for (int c=0;c<4;++c){ f32x4 z = {}; acc[r][c] = z; }
  }
  for (int k0=0; k0<K; k0+=32){
    #pragma unroll
    for (int i=0;i<2;++i){
      int ch = t + i*256;
      int r = ch>>2, ko = (ch&3)*8;
      *(uint4*)(&As[r][ko]) = *(const uint4*)(A + (size_t)(row0+r)*K + k0 + ko);
    }
    {
      int r = t>>2, ko = (t&3)*8;
      *(uint4*)(&Bs[r][ko]) = *(const uint4*)(Wt + (size_t)(col0+r)*K + k0 + ko);
    }
    __syncthreads();
    bf16x8 af0 = *(const bf16x8*)(&As[w*32 + lr][q*8]);
    bf16x8 af1 = *(const bf16x8*)(&As[w*32 + 16 + lr][q*8]);
    #pragma unroll
    for (int c=0;c<4;++c){
      bf16x8 bfr = *(const bf16x8*)(&Bs[c*16 + lr][q*8]);
      acc[0][c] = __builtin_amdgcn_mfma_f32_16x16x32_bf16(af0, bfr, acc[0][c], 0,0,0);
      acc[1][c] = __builtin_amdgcn_mfma_f32_16x16x32_bf16(af1, bfr, acc[1][c], 0,0,0);
    }
    __syncthreads();
  }
  float bcol[4];
  #pragma unroll
  for (int c=0;c<4;++c){
    int col = col0 + c*16 + lr;
    float bv = 0.f;
    if (flags & 4) bv += bias[col];
    if (flags & 2) bv += rowbias[(size_t)bid[row0]*Ncol + col];
    bcol[c] = bv;
  }
  #pragma unroll
  for (int r=0;r<2;++r){
    #pragma unroll
    for (int c=0;c<4;++c){
      int col = col0 + c*16 + lr;
      #pragma unroll
      for (int i=0;i<4;++i){
        int row = row0 + w*32 + r*16 + q*4 + i;
        float v = acc[r][c][i] + bcol[c];
        if (flags & 1) v = fmaxf(v, 0.f);
        C[(size_t)row*Ncol + col] = (u16)f2bf(v);
      }
    }
  }
}

// ---------------- fused attention v3 (H=256): 128-row blocks, k_mm-staged B, S register-resident.
template<int DIN>
__global__ __launch_bounds__(256,2) void k_attn3(const u16* __restrict__ V, const u16* __restrict__ Wt,
        const float* __restrict__ cb, const int* __restrict__ bid, float* __restrict__ o){
  constexpr int KS = DIN/32;
  __shared__ u16 As[128][40];
  __shared__ u16 Bs[64][40];
  const int t = threadIdx.x;
  const int node0 = blockIdx.x*128;    // 128 | 2048 -> single batch per block
  const int lane = t & 63, w = t >> 6;
  const int lr = lane & 15, q = lane >> 4;
  f32x4 sacc[4][2][4];
  #pragma unroll
  for (int cc=0;cc<4;++cc)
    #pragma unroll
    for (int rf=0;rf<2;++rf)
      #pragma unroll
      for (int cf=0;cf<4;++cf){ f32x4 z = {}; sacc[cc][rf][cf] = z; }
  // ---- S phase ----
  #pragma unroll
  for (int cc=0;cc<4;++cc){
    for (int k0=0;k0<KS;++k0){
      #pragma unroll
      for (int i=0;i<2;++i){
        int ch = t + i*256;
        int r = ch>>2, ko = (ch&3)*8;
        *(uint4*)(&As[r][ko]) = *(const uint4*)(V + (size_t)(node0+r)*DIN + k0*32 + ko);
      }
      {
        int r = t>>2, ko = (t&3)*8;
        *(uint4*)(&Bs[r][ko]) = *(const uint4*)(Wt + (size_t)(cc*64+r)*DIN + k0*32 + ko);
      }
      __syncthreads();
      bf16x8 a0 = *(const bf16x8*)(&As[w*32 + lr][q*8]);
      bf16x8 a1 = *(const bf16x8*)(&As[w*32 + 16 + lr][q*8]);
      #pragma unroll
      for (int cf=0;cf<4;++cf){
        bf16x8 b = *(const bf16x8*)(&Bs[cf*16 + lr][q*8]);
        sacc[cc][0][cf] = __builtin_amdgcn_mfma_f32_16x16x32_bf16(a0, b, sacc[cc][0][cf], 0,0,0);
        sacc[cc][1][cf] = __builtin_amdgcn_mfma_f32_16x16x32_bf16(a1, b, sacc[cc][1][cf], 0,0,0);
      }
      __syncthreads();
    }
  }
  // + bias
  #pragma unroll
  for (int cc=0;cc<4;++cc)
    #pragma unroll
    for (int cf=0;cf<4;++cf){
      float bv = cb[cc*64 + cf*16 + lr];
      #pragma unroll
      for (int rf=0;rf<2;++rf)
        #pragma unroll
        for (int i=0;i<4;++i) sacc[cc][rf][cf][i] += bv;
    }
  // ---- in-register softmax stats per row (rf,i) ----
  float m[2][4], iz[2][4];
  #pragma unroll
  for (int rf=0;rf<2;++rf){
    #pragma unroll
    for (int i=0;i<4;++i){
      float mx = -1e30f;
      #pragma unroll
      for (int cc=0;cc<4;++cc)
        #pragma unroll
        for (int cf=0;cf<4;++cf) mx = fmaxf(mx, sacc[cc][rf][cf][i]);
      #pragma unroll
      for (int off=1; off<16; off<<=1) mx = fmaxf(mx, __shfl_xor(mx, off));
      float zz = 0.f;
      #pragma unroll
      for (int cc=0;cc<4;++cc)
        #pragma unroll
        for (int cf=0;cf<4;++cf) zz += __expf(sacc[cc][rf][cf][i] - mx);
      #pragma unroll
      for (int off=1; off<16; off<<=1) zz += __shfl_xor(zz, off);
      m[rf][i] = mx; iz[rf][i] = 1.0f/zz;
    }
  }
  // ---- F phase: consume chunk-by-chunk ----
  const int bb = bid[node0];
  #pragma unroll
  for (int cc=0;cc<4;++cc){
    f32x4 facc[2][4];
    #pragma unroll
    for (int rf=0;rf<2;++rf)
      #pragma unroll
      for (int cf=0;cf<4;++cf){ f32x4 z = {}; facc[rf][cf] = z; }
    for (int k0=0;k0<KS;++k0){
      #pragma unroll
      for (int i=0;i<2;++i){
        int ch = t + i*256;
        int r = ch>>2, ko = (ch&3)*8;
        *(uint4*)(&As[r][ko]) = *(const uint4*)(V + (size_t)(node0+r)*DIN + k0*32 + ko);
      }
      {
        int r = t>>2, ko = (t&3)*8;
        *(uint4*)(&Bs[r][ko]) = *(const uint4*)(Wt + (size_t)(256+cc*64+r)*DIN + k0*32 + ko);
      }
      __syncthreads();
      bf16x8 a0 = *(const bf16x8*)(&As[w*32 + lr][q*8]);
      bf16x8 a1 = *(const bf16x8*)(&As[w*32 + 16 + lr][q*8]);
      #pragma unroll
      for (int cf=0;cf<4;++cf){
        bf16x8 b = *(const bf16x8*)(&Bs[cf*16 + lr][q*8]);
        facc[0][cf] = __builtin_amdgcn_mfma_f32_16x16x32_bf16(a0, b, facc[0][cf], 0,0,0);
        facc[1][cf] = __builtin_amdgcn_mfma_f32_16x16x32_bf16(a1, b, facc[1][cf], 0,0,0);
      }
      __syncthreads();
    }
    #pragma unroll
    for (int cf=0;cf<4;++cf){
      float fb = cb[256 + cc*64 + cf*16 + lr];
      float cs = 0.f;
      #pragma unroll
      for (int rf=0;rf<2;++rf)
        #pragma unroll
        for (int i=0;i<4;++i){
          float p = __expf(sacc[cc][rf][cf][i] - m[rf][i]) * iz[rf][i];
          cs = fmaf(p, facc[rf][cf][i] + fb, cs);
        }
      cs += __shfl_xor(cs, 16);
      cs += __shfl_xor(cs, 32);
      if (q == 0) atomicAdd(&o[bb*256 + cc*64 + cf*16 + lr], cs);
    }
  }
}

// ---------------- fused attention (H=64 small layer)
template<int DIN, int H>
__global__ __launch_bounds__(256) void k_attnf(const u16* __restrict__ V, const u16* __restrict__ Wt,
        const float* __restrict__ cb, const int* __restrict__ bid, float* __restrict__ o){
  constexpr int CF  = H/64;
  constexpr int KS  = DIN/32;
  constexpr int AST = DIN + 8;
  constexpr int SST = H + 4;
  __shared__ u16 As[32*AST];
  __shared__ u16 Ssh[32*SST];
  __shared__ u16 Fsh[32*SST];
  __shared__ float mZ[2][32];
  const int t = threadIdx.x;
  const int node0 = blockIdx.x*32;
  const int lane = t & 63, w = t >> 6;
  const int lr = lane & 15, q = lane >> 4;
  #pragma unroll
  for (int i = 0; i < (32*DIN/8)/256; ++i){
    int ch = t + i*256;
    int r = ch / (DIN/8), co = (ch % (DIN/8))*8;
    *(uint4*)(&As[r*AST + co]) = *(const uint4*)(V + (size_t)(node0+r)*DIN + co);
  }
  __syncthreads();
  #pragma unroll
  for (int ph = 0; ph < 2; ++ph){
    f32x4 acc[2][CF];
    #pragma unroll
    for (int r=0;r<2;++r){
      #pragma unroll
      for (int c=0;c<CF;++c){ f32x4 z = {}; acc[r][c] = z; }
    }
    #pragma unroll
    for (int k=0;k<KS;++k){
      bf16x8 a0 = *(const bf16x8*)(&As[lr*AST + k*32 + q*8]);
      bf16x8 a1 = *(const bf16x8*)(&As[(16+lr)*AST + k*32 + q*8]);
      #pragma unroll
      for (int c=0;c<CF;++c){
        int col = ph*H + w*(16*CF) + c*16 + lr;
        bf16x8 b = *(const bf16x8*)(Wt + (size_t)col*DIN + k*32 + q*8);
        acc[0][c] = __builtin_amdgcn_mfma_f32_16x16x32_bf16(a0, b, acc[0][c], 0,0,0);
        acc[1][c] = __builtin_amdgcn_mfma_f32_16x16x32_bf16(a1, b, acc[1][c], 0,0,0);
      }
    }
    u16* dst = ph ? Fsh : Ssh;
    #pragma unroll
    for (int c=0;c<CF;++c){
      int colL = w*(16*CF) + c*16 + lr;
      float bias = cb[ph*H + colL];
      #pragma unroll
      for (int rf=0; rf<2; ++rf){
        #pragma unroll
        for (int i=0;i<4;++i){
          int row = rf*16 + q*4 + i;
          dst[row*SST + colL] = (u16)f2bf(acc[rf][c][i] + bias);
        }
      }
    }
    if (ph==0){
      __syncthreads();
      #pragma unroll
      for (int nn=0; nn<8; ++nn){
        int n = w*8 + nn;
        constexpr int VPL = H/64;
        float vals[VPL]; float mx = -1e30f;
        if constexpr (VPL == 4){
          uint2 uv = *(const uint2*)(&Ssh[n*SST + lane*4]);
          vals[0]=bflo(uv.x); vals[1]=bfhi(uv.x); vals[2]=bflo(uv.y); vals[3]=bfhi(uv.y);
          mx = fmaxf(fmaxf(vals[0],vals[1]), fmaxf(vals[2],vals[3]));
        } else {
          vals[0] = bflo((u32)Ssh[n*SST + lane]);
          mx = vals[0];
        }
        mx = wave_max(mx);
        float z = 0.f;
        #pragma unroll
        for (int i=0;i<VPL;++i) z += __expf(vals[i]-mx);
        z = wave_sum(z);
        if (lane==0){ mZ[0][n]=mx; mZ[1][n]=1.0f/z; }
      }
    }
  }
  __syncthreads();
  const int col = t % H;
  constexpr int NPER = 32*H/256;
  const int n0 = (t / H) * NPER;
  float acc2 = 0.f;
  #pragma unroll 8
  for (int n=n0; n<n0+NPER; ++n){
    float s = bflo((u32)Ssh[n*SST + col]);
    float f = bflo((u32)Fsh[n*SST + col]);
    acc2 = fmaf(__expf(s - mZ[0][n]) * mZ[1][n], f, acc2);
  }
  atomicAdd(&o[bid[node0]*H + col], acc2);
}

// ---------------- g update, parallel-K
template<int H, bool HASG>
__global__ __launch_bounds__(256) void k_gup2(const float* __restrict__ o, const float* __restrict__ gprev,
        const float* __restrict__ gw, const float* __restrict__ gb, float* __restrict__ gout){
  constexpr int KT = H + (HASG ? 256 : 0);
  constexpr int KPS = KT/8;
  __shared__ float vsh[KT];
  __shared__ float red[8][33];
  const int b = blockIdx.x;
  const int c = threadIdx.x & 31;
  const int s = threadIdx.x >> 5;
  const int col = blockIdx.y*32 + c;
  for (int k=threadIdx.x; k<KT; k+=256)
    vsh[k] = (k < H) ? o[b*H + k] : gprev[b*256 + (k - H)];
  __syncthreads();
  float acc = 0.f;
  const float* wp = gw + (size_t)(s*KPS)*256 + col;
  #pragma unroll 8
  for (int i=0;i<KPS;++i)
    acc = fmaf(vsh[s*KPS+i], wp[(size_t)i*256], acc);
  red[s][c] = acc;
  __syncthreads();
  if (s==0){
    float sum = 0.f;
    #pragma unroll
    for (int j=0;j<8;++j) sum += red[j][c];
    float gp = HASG ? gprev[b*256+col] : 0.f;
    gout[b*256+col] = gp + sum + gb[col];
  }
}

// ---------------- per-batch head bias, parallel-K
__global__ __launch_bounds__(256) void k_hb2(const float* __restrict__ g2, const float* __restrict__ o1w,
                                             const float* __restrict__ o1b, float* __restrict__ hb){
  __shared__ float vsh[256];
  __shared__ float red[8][33];
  const int b = blockIdx.x;
  const int c = threadIdx.x & 31;
  const int s = threadIdx.x >> 5;
  const int col = blockIdx.y*32 + c;
  vsh[threadIdx.x] = g2[b*256 + threadIdx.x];
  __syncthreads();
  float acc = 0.f;
  const float* wp = o1w + (size_t)(64 + s*32)*256 + col;
  #pragma unroll 8
  for (int i=0;i<32;++i)
    acc = fmaf(vsh[s*32+i], wp[(size_t)i*256], acc);
  red[s][c] = acc;
  __syncthreads();
  if (s==0){
    float sum = 0.f;
    #pragma unroll
    for (int j=0;j<8;++j) sum += red[j][c];
    hb[b*256+col] = sum + o1b[col];
  }
}

// ---------------- head layer 2 + pack
__global__ __launch_bounds__(256) void k_head2(const u16* __restrict__ z, const float* __restrict__ w,
        const float* __restrict__ bvec, const int* __restrict__ bid, const int* __restrict__ batches,
        float* __restrict__ out){
  __shared__ float zs[16][257];
  int t = threadIdx.x;
  int g0 = blockIdx.x*16;
  #pragma unroll
  for (int i=0;i<2;++i){
    int ch = t + i*256;
    int v = ch>>5, ko=(ch&31)*8;
    uint4 qv = *(const uint4*)(z + (size_t)(g0+v)*256 + ko);
    zs[v][ko+0]=bflo(qv.x); zs[v][ko+1]=bfhi(qv.x);
    zs[v][ko+2]=bflo(qv.y); zs[v][ko+3]=bfhi(qv.y);
    zs[v][ko+4]=bflo(qv.z); zs[v][ko+5]=bfhi(qv.z);
    zs[v][ko+6]=bflo(qv.w); zs[v][ko+7]=bfhi(qv.w);
  }
  __syncthreads();
  int v = t >> 4, c = t & 15;
  if (c < DIM_A){
    float acc = bvec[c];
    for (int k=0;k<256;++k) acc = fmaf(zs[v][k], w[k*DIM_A + c], acc);
    int node = g0 + v;
    int bb = bid[node];
    out[(size_t)bb*OUT_PER_B + (size_t)(node - batches[bb])*DIM_A + c] = acc;
  }
}

extern "C" void kernel_launch(void* const* d_in, const int* in_sizes, int n_in,
                              void* d_out, int out_size, void* d_ws, size_t ws_size,
                              hipStream_t stream){
  const float* x       = (const float*)d_in[0];
  const int*   ei      = (const int*)d_in[1];
  const int*   batches = (const int*)d_in[2];
  const float* conv1_w = (const float*)d_in[4];
  const float* conv1_b = (const float*)d_in[5];
  const float* conv2_w = (const float*)d_in[6];
  const float* conv2_b = (const float*)d_in[7];
  const float* g0_aw = (const float*)d_in[8];  const float* g0_ab = (const float*)d_in[9];
  const float* g0_fw = (const float*)d_in[10]; const float* g0_fb = (const float*)d_in[11];
  const float* g0_gw = (const float*)d_in[12]; const float* g0_gb = (const float*)d_in[13];
  const float* g1_aw = (const float*)d_in[14]; const float* g1_ab = (const float*)d_in[15];
  const float* g1_fw = (const float*)d_in[16]; const float* g1_fb = (const float*)d_in[17];
  const float* g1_gw = (const float*)d_in[18]; const float* g1_gb = (const float*)d_in[19];
  const float* g2_aw = (const float*)d_in[20]; const float* g2_ab = (const float*)d_in[21];
  const float* g2_fw = (const float*)d_in[22]; const float* g2_fb = (const float*)d_in[23];
  const float* g2_gw = (const float*)d_in[24]; const float* g2_gb = (const float*)d_in[25];
  const float* o1_w  = (const float*)d_in[26]; const float* o1_b  = (const float*)d_in[27];
  const float* o2_w  = (const float*)d_in[28]; const float* o2_b  = (const float*)d_in[29];
  float* out = (float*)d_out;

  char* W = (char*)d_ws;
  size_t off = 0;
  auto alloc = [&](size_t bytes)->void*{
    off = (off + 255) & ~(size_t)255;
    void* p = W + off; off += bytes; return p;
  };
  float* dis      = (float*)alloc(N_NODES*4);
  int*   cnt      = (int*)  alloc(N_NODES*4);
  int*   bid      = (int*)  alloc(N_NODES*4);
  int*   rowstart = (int*)  alloc(N_NODES*4);
  int*   cursor   = (int*)  alloc(N_NODES*4);
  int*   csr_src  = (int*)  alloc(N_EDGES*4);
  int*   bsum     = (int*)  alloc(256*4);
  int*   boff     = (int*)  alloc(256*4);
  float* o0       = (float*)alloc(NB*256*4);
  float* o1a      = (float*)alloc(NB*256*4);
  float* o2a      = (float*)alloc(NB*256*4);
  float* gv0      = (float*)alloc(NB*256*4);
  float* gv1      = (float*)alloc(NB*256*4);
  float* gv2      = (float*)alloc(NB*256*4);
  float* hb       = (float*)alloc(NB*256*4);
  float* cb0      = (float*)alloc(512*4);
  float* cb1      = (float*)alloc(512*4);
  float* cb2      = (float*)alloc(128*4);
  u16* conv1T = (u16*)alloc(32768*2);
  u16* Wt0    = (u16*)alloc(65536*2);
  u16* Wt1    = (u16*)alloc(131072*2);
  u16* conv2T = (u16*)alloc(16384*2);
  u16* Wt2    = (u16*)alloc(8192*2);
  u16* o1T    = (u16*)alloc(16384*2);
  u16* h1b    = (u16*)alloc((size_t)N_NODES*DIM_H1*2);   // 29.4 MB; reused as z
  u16* X      = (u16*)alloc((size_t)N_NODES*DIM_IN*2);   // 14.7 MB: xb; later hw2b | h2b
  u16* agg1b  = (u16*)alloc((size_t)N_NODES*DIM_IN*2);   // 14.7 MB
  u16* xb    = X;
  u16* hw2b  = X;
  u16* h2b   = X + (size_t)N_NODES*DIM_H2;
  u16* z     = h1b;

  // ---- init + CSR ----
  k_init <<<OUT_SZ/256, 256, 0, stream>>>(cnt, bid, batches, o0, out);
  k_deg  <<<N_EDGES/256, 256, 0, stream>>>(ei, cnt);
  k_scanA<<<N_NODES/256, 256, 0, stream>>>(cnt, bsum);
  k_scanB<<<1, 256, 0, stream>>>(bsum, boff);
  k_scanC<<<N_NODES/256, 256, 0, stream>>>(cnt, boff, rowstart, cursor, dis);
  k_place<<<N_EDGES/256, 256, 0, stream>>>(ei, cursor, csr_src);

  // ---- conversions / weight prep ----
  k_cvtx <<<N_NODES*DIM_IN/4/256, 256, 0, stream>>>(x, xb);
  k_prep <<<(270336+1152+255)/256, 256, 0, stream>>>(conv1_w, g0_aw, g0_fw, g1_aw, g1_fw, conv2_w,
            g2_aw, g2_fw, o1_w, g0_ab, g0_fb, g1_ab, g1_fb, g2_ab, g2_fb,
            conv1T, Wt0, Wt1, conv2T, Wt2, o1T, cb0, cb1, cb2);

  // ---- GCN1: aggregate then GEMM(+bias,relu) ----
  k_agg1b<<<N_NODES/4, 256, 0, stream>>>(xb, dis, rowstart, cnt, csr_src, agg1b);
  k_mm   <<<dim3(N_NODES/128, 4), 256, 0, stream>>>(agg1b, conv1T, conv1_b, nullptr, nullptr,
                                                    h1b, DIM_IN, DIM_H1, 4|1);
  // ---- fused attention 0 on xb ----
  k_attn3<128><<<N_NODES/128, 256, 0, stream>>>(xb, Wt0, cb0, bid, o0);
  k_gup2<256,false><<<dim3(NB,8), 256, 0, stream>>>(o0, nullptr, g0_gw, g0_gb, gv0);

  // ---- fused attention 1 on h1b ----
  k_attn3<256><<<N_NODES/128, 256, 0, stream>>>(h1b, Wt1, cb1, bid, o1a);
  k_gup2<256,true><<<dim3(NB,8), 256, 0, stream>>>(o1a, gv0, g1_gw, g1_gb, gv1);

  // ---- GCN2: GEMM then aggregate(+bias,relu) ----
  k_mm   <<<dim3(N_NODES/128, 1), 256, 0, stream>>>(h1b, conv2T, nullptr, nullptr, nullptr,
                                                    hw2b, DIM_H1, DIM_H2, 0);
  k_agg2b<<<N_NODES/4, 256, 0, stream>>>(hw2b, dis, rowstart, cnt, csr_src, conv2_b, h2b);

  // ---- fused attention 2 on h2b ----
  k_attnf<64,64><<<N_NODES/32, 256, 0, stream>>>(h2b, Wt2, cb2, bid, o2a);
  k_gup2<64,true><<<dim3(NB,8), 256, 0, stream>>>(o2a, gv1, g2_gw, g2_gb, gv2);

  // ---- head ----
  k_hb2  <<<dim3(NB,8), 256, 0, stream>>>(gv2, o1_w, o1_b, hb);
  k_mm   <<<dim3(N_NODES/128, 4), 256, 0, stream>>>(h2b, o1T, nullptr, hb, bid, z, DIM_H2, 256, 2|1);
  k_head2<<<N_NODES/16, 256, 0, stream>>>(z, o2_w, o2_b, bid, batches, out);

  (void)in_sizes; (void)n_in; (void)out_size; (void)ws_size;
}

// Round 8
// 423.347 us; speedup vs baseline: 1.2743x; 1.0397x over previous
//
#include <hip/hip_runtime.h>
#include <math.h>

#define N_NODES 57344
#define N_EDGES 458752
#define DIM_IN 128
#define DIM_H1 256
#define DIM_H2 64
#define DIM_A 11
#define NB 16
#define MAXB 4096
#define OUT_PER_B (MAXB*DIM_A)   // 45056
#define OUT_SZ (NB*OUT_PER_B)    // 720896
#define NEG_FILL (-1.0e30f)

typedef unsigned short u16;
typedef unsigned int u32;
typedef __bf16 bf16x8 __attribute__((ext_vector_type(8)));
typedef float f32x4 __attribute__((ext_vector_type(4)));

__device__ __forceinline__ float bflo(u32 u){ union{u32 i; float f;} x; x.i = u<<16; return x.f; }
__device__ __forceinline__ float bfhi(u32 u){ union{u32 i; float f;} x; x.i = u & 0xFFFF0000u; return x.f; }
__device__ __forceinline__ u32 f2bf(float f){ union{float f; u32 i;} x; x.f=f; return (x.i + 0x7FFFu + ((x.i>>16)&1u)) >> 16; }

__device__ __forceinline__ float wave_max(float v){
  #pragma unroll
  for (int off=32; off; off>>=1) v = fmaxf(v, __shfl_xor(v, off));
  return v;
}
__device__ __forceinline__ float wave_sum(float v){
  #pragma unroll
  for (int off=32; off; off>>=1) v += __shfl_xor(v, off);
  return v;
}

// ---------------- init
__global__ __launch_bounds__(256) void k_init(int* cnt, int* bid, const int* __restrict__ batches,
                                              float* oacc, float* out){
  int i = blockIdx.x*256 + threadIdx.x;
  if (i < N_NODES){
    cnt[i] = 0;
    int lo=0, hi=NB-1;
    while (lo<hi){ int mid=(lo+hi+1)>>1; if (batches[mid]<=i) lo=mid; else hi=mid-1; }
    bid[i]=lo;
  }
  if (i < 3*NB*256) oacc[i] = 0.0f;
  if (i < OUT_SZ) out[i] = NEG_FILL;
}

__global__ __launch_bounds__(256) void k_deg(const int* __restrict__ ei, int* cnt){
  int e = blockIdx.x*256 + threadIdx.x;
  if (e < N_EDGES) atomicAdd(&cnt[ei[N_EDGES + e]], 1);
}

__global__ __launch_bounds__(256) void k_scanA(const int* __restrict__ cnt, int* bsum){
  __shared__ int s[256];
  int t=threadIdx.x; int i=blockIdx.x*256+t;
  s[t]=cnt[i]; __syncthreads();
  for (int off=128; off; off>>=1){ if (t<off) s[t]+=s[t+off]; __syncthreads(); }
  if (t==0) bsum[blockIdx.x]=s[0];
}
__global__ __launch_bounds__(256) void k_scanB(const int* __restrict__ bsum, int* boff){
  __shared__ int s[256];
  int t=threadIdx.x;
  int v = (t < N_NODES/256) ? bsum[t] : 0;
  s[t]=v; __syncthreads();
  for (int o=1;o<256;o<<=1){
    int a = (t>=o) ? s[t-o] : 0;
    __syncthreads();
    s[t] += a;
    __syncthreads();
  }
  if (t < N_NODES/256) boff[t] = s[t] - v;
}
__global__ __launch_bounds__(256) void k_scanC(const int* __restrict__ cnt, const int* __restrict__ boff,
                                               int* rowstart, int* cursor, float* dis){
  __shared__ int s[256];
  int t=threadIdx.x; int i=blockIdx.x*256+t;
  int v=cnt[i]; s[t]=v; __syncthreads();
  for (int off=1; off<256; off<<=1){
    int add = (t>=off)? s[t-off] : 0;
    __syncthreads();
    s[t]+=add;
    __syncthreads();
  }
  int rs = boff[blockIdx.x] + s[t] - v;
  rowstart[i]=rs; cursor[i]=rs;
  dis[i] = rsqrtf(1.0f + (float)v);
}
__global__ __launch_bounds__(256) void k_place(const int* __restrict__ ei, int* cursor, int* csr_src){
  int e = blockIdx.x*256 + threadIdx.x;
  if (e < N_EDGES){
    int s = ei[e], d = ei[N_EDGES+e];
    int slot = atomicAdd(&cursor[d], 1);
    csr_src[slot] = s;
  }
}

// ---------------- x fp32 -> bf16
__global__ __launch_bounds__(256) void k_cvtx(const float* __restrict__ x, u16* __restrict__ xb){
  int i = blockIdx.x*256 + threadIdx.x;
  float4 v = *(const float4*)(x + (size_t)i*4);
  u32 lo = f2bf(v.x) | (f2bf(v.y)<<16);
  u32 hi = f2bf(v.z) | (f2bf(v.w)<<16);
  *(uint2*)(xb + (size_t)i*4) = make_uint2(lo, hi);
}

// ---------------- weight prep
__global__ __launch_bounds__(256) void k_prep(
    const float* __restrict__ conv1_w, const float* __restrict__ g0_aw, const float* __restrict__ g0_fw,
    const float* __restrict__ g1_aw, const float* __restrict__ g1_fw, const float* __restrict__ conv2_w,
    const float* __restrict__ g2_aw, const float* __restrict__ g2_fw, const float* __restrict__ o1_w,
    const float* __restrict__ g0_ab, const float* __restrict__ g0_fb,
    const float* __restrict__ g1_ab, const float* __restrict__ g1_fb,
    const float* __restrict__ g2_ab, const float* __restrict__ g2_fb,
    u16* conv1T, u16* Wt0, u16* Wt1, u16* conv2T, u16* Wt2, u16* o1T,
    float* cb0, float* cb1, float* cb2){
  int i = blockIdx.x*256 + threadIdx.x;
  if (i < 32768){ int k=i>>8, n=i&255; conv1T[n*128+k]=(u16)f2bf(conv1_w[i]); return; } i-=32768;
  if (i < 32768){ int k=i>>8, n=i&255; Wt0[n*128+k]=(u16)f2bf(g0_aw[i]); return; } i-=32768;
  if (i < 32768){ int k=i>>8, n=i&255; Wt0[(256+n)*128+k]=(u16)f2bf(g0_fw[i]); return; } i-=32768;
  if (i < 65536){ int k=i>>8, n=i&255; Wt1[n*256+k]=(u16)f2bf(g1_aw[i]); return; } i-=65536;
  if (i < 65536){ int k=i>>8, n=i&255; Wt1[(256+n)*256+k]=(u16)f2bf(g1_fw[i]); return; } i-=65536;
  if (i < 16384){ int k=i>>6, n=i&63;  conv2T[n*256+k]=(u16)f2bf(conv2_w[i]); return; } i-=16384;
  if (i < 4096) { int k=i>>6, n=i&63;  Wt2[n*64+k]=(u16)f2bf(g2_aw[i]); return; } i-=4096;
  if (i < 4096) { int k=i>>6, n=i&63;  Wt2[(64+n)*64+k]=(u16)f2bf(g2_fw[i]); return; } i-=4096;
  if (i < 16384){ int k=i>>8, n=i&255; o1T[n*64+k]=(u16)f2bf(o1_w[i]); return; } i-=16384;
  if (i < 256){ cb0[i]=g0_ab[i]; return; } i-=256;
  if (i < 256){ cb0[256+i]=g0_fb[i]; return; } i-=256;
  if (i < 256){ cb1[i]=g1_ab[i]; return; } i-=256;
  if (i < 256){ cb1[256+i]=g1_fb[i]; return; } i-=256;
  if (i < 64) { cb2[i]=g2_ab[i]; return; } i-=64;
  if (i < 64) { cb2[64+i]=g2_fb[i]; return; }
}

// ---------------- GCN1 aggregation, 4x unrolled
__global__ __launch_bounds__(256) void k_agg1b(const u16* __restrict__ xb, const float* __restrict__ dis,
        const int* __restrict__ rowstart, const int* __restrict__ cnt, const int* __restrict__ csr_src,
        u16* __restrict__ agg){
  int d = (blockIdx.x*256 + threadIdx.x) >> 6;
  int lane = threadIdx.x & 63;
  float dd = dis[d];
  u32 u = *(const u32*)(xb + (size_t)d*DIM_IN + lane*2);
  float ax = bflo(u)*dd*dd, ay = bfhi(u)*dd*dd;
  int base = rowstart[d], c = cnt[d];
  int j = 0;
  for (; j+4 <= c; j += 4){
    int s0=csr_src[base+j+0], s1=csr_src[base+j+1], s2=csr_src[base+j+2], s3=csr_src[base+j+3];
    u32 u0=*(const u32*)(xb+(size_t)s0*DIM_IN+lane*2);
    u32 u1=*(const u32*)(xb+(size_t)s1*DIM_IN+lane*2);
    u32 u2=*(const u32*)(xb+(size_t)s2*DIM_IN+lane*2);
    u32 u3=*(const u32*)(xb+(size_t)s3*DIM_IN+lane*2);
    float n0=dis[s0]*dd, n1=dis[s1]*dd, n2=dis[s2]*dd, n3=dis[s3]*dd;
    ax=fmaf(bflo(u0),n0,ax); ay=fmaf(bfhi(u0),n0,ay);
    ax=fmaf(bflo(u1),n1,ax); ay=fmaf(bfhi(u1),n1,ay);
    ax=fmaf(bflo(u2),n2,ax); ay=fmaf(bfhi(u2),n2,ay);
    ax=fmaf(bflo(u3),n3,ax); ay=fmaf(bfhi(u3),n3,ay);
  }
  for (; j<c; ++j){
    int s = csr_src[base+j];
    float nrm = dis[s]*dd;
    u32 us = *(const u32*)(xb + (size_t)s*DIM_IN + lane*2);
    ax = fmaf(bflo(us), nrm, ax);
    ay = fmaf(bfhi(us), nrm, ay);
  }
  *(u32*)(agg + (size_t)d*DIM_IN + lane*2) = f2bf(ax) | (f2bf(ay)<<16);
}

// ---------------- GCN2 aggregation, 4x unrolled
__global__ __launch_bounds__(256) void k_agg2b(const u16* __restrict__ hw, const float* __restrict__ dis,
        const int* __restrict__ rowstart, const int* __restrict__ cnt, const int* __restrict__ csr_src,
        const float* __restrict__ b2, u16* __restrict__ h2){
  int d = (blockIdx.x*256 + threadIdx.x) >> 6;
  int lane = threadIdx.x & 63;
  float dd = dis[d];
  float acc = bflo((u32)hw[(size_t)d*DIM_H2 + lane]) * dd*dd;
  int base = rowstart[d], c = cnt[d];
  int j = 0;
  for (; j+4 <= c; j += 4){
    int s0=csr_src[base+j+0], s1=csr_src[base+j+1], s2=csr_src[base+j+2], s3=csr_src[base+j+3];
    u16 v0=hw[(size_t)s0*DIM_H2+lane], v1=hw[(size_t)s1*DIM_H2+lane];
    u16 v2=hw[(size_t)s2*DIM_H2+lane], v3=hw[(size_t)s3*DIM_H2+lane];
    float n0=dis[s0]*dd, n1=dis[s1]*dd, n2=dis[s2]*dd, n3=dis[s3]*dd;
    acc=fmaf(bflo((u32)v0),n0,acc); acc=fmaf(bflo((u32)v1),n1,acc);
    acc=fmaf(bflo((u32)v2),n2,acc); acc=fmaf(bflo((u32)v3),n3,acc);
  }
  for (; j<c; ++j){
    int s = csr_src[base+j];
    acc = fmaf(bflo((u32)hw[(size_t)s*DIM_H2 + lane]), dis[s]*dd, acc);
  }
  h2[(size_t)d*DIM_H2 + lane] = (u16)f2bf(fmaxf(acc + b2[lane], 0.0f));
}

// ---------------- bf16 MFMA GEMM (conv1 / conv2 / head1)
__global__ __launch_bounds__(256) void k_mm(const u16* __restrict__ A, const u16* __restrict__ Wt,
        const float* __restrict__ bias, const float* __restrict__ rowbias, const int* __restrict__ bid,
        u16* __restrict__ C, int K, int Ncol, int flags){
  __shared__ u16 As[128][40];
  __shared__ u16 Bs[64][40];
  const int t = threadIdx.x;
  const int row0 = blockIdx.x*128, col0 = blockIdx.y*64;
  const int lane = t & 63, w = t >> 6;
  const int lr = lane & 15, q = lane >> 4;
  f32x4 acc[2][4];
  #pragma unroll
  for (int r=0;r<2;++r){
    #pragma unroll
    for (int c=0;c<4;++c){ f32x4 z = {}; acc[r][c] = z; }
  }
  for (int k0=0; k0<K; k0+=32){
    #pragma unroll
    for (int i=0;i<2;++i){
      int ch = t + i*256;
      int r = ch>>2, ko = (ch&3)*8;
      *(uint4*)(&As[r][ko]) = *(const uint4*)(A + (size_t)(row0+r)*K + k0 + ko);
    }
    {
      int r = t>>2, ko = (t&3)*8;
      *(uint4*)(&Bs[r][ko]) = *(const uint4*)(Wt + (size_t)(col0+r)*K + k0 + ko);
    }
    __syncthreads();
    bf16x8 af0 = *(const bf16x8*)(&As[w*32 + lr][q*8]);
    bf16x8 af1 = *(const bf16x8*)(&As[w*32 + 16 + lr][q*8]);
    #pragma unroll
    for (int c=0;c<4;++c){
      bf16x8 bfr = *(const bf16x8*)(&Bs[c*16 + lr][q*8]);
      acc[0][c] = __builtin_amdgcn_mfma_f32_16x16x32_bf16(af0, bfr, acc[0][c], 0,0,0);
      acc[1][c] = __builtin_amdgcn_mfma_f32_16x16x32_bf16(af1, bfr, acc[1][c], 0,0,0);
    }
    __syncthreads();
  }
  float bcol[4];
  #pragma unroll
  for (int c=0;c<4;++c){
    int col = col0 + c*16 + lr;
    float bv = 0.f;
    if (flags & 4) bv += bias[col];
    if (flags & 2) bv += rowbias[(size_t)bid[row0]*Ncol + col];
    bcol[c] = bv;
  }
  #pragma unroll
  for (int r=0;r<2;++r){
    #pragma unroll
    for (int c=0;c<4;++c){
      int col = col0 + c*16 + lr;
      #pragma unroll
      for (int i=0;i<4;++i){
        int row = row0 + w*32 + r*16 + q*4 + i;
        float v = acc[r][c][i] + bcol[c];
        if (flags & 1) v = fmaxf(v, 0.f);
        C[(size_t)row*Ncol + col] = (u16)f2bf(v);
      }
    }
  }
}

// ---------------- fused attention v4 (H=256): A staged ONCE, double-buffered B chunks.
// 8 col-chunks (4 S + 4 F) of 64 cols; S in registers (128 VGPR); in-register softmax;
// F consumed chunk-by-chunk. One sync per k-step. Wt=[2H][DIN], cb=[ab|fb].
template<int DIN>
__global__ __launch_bounds__(256,2) void k_attn4(const u16* __restrict__ V, const u16* __restrict__ Wt,
        const float* __restrict__ cb, const int* __restrict__ bid, float* __restrict__ o){
  constexpr int KS  = DIN/32;
  constexpr int NJ  = 8*KS;
  constexpr int AST = DIN + 8;
  __shared__ u16 As[128*AST];     // DIN=256: 67.6 KB, DIN=128: 34.8 KB
  __shared__ u16 Bs[2][64][40];   // 10 KB double-buffered
  const int t = threadIdx.x;
  const int node0 = blockIdx.x*128;   // 128 | 2048 -> single batch per block
  const int lane = t & 63, w = t >> 6;
  const int lr = lane & 15, q = lane >> 4;
  // stage A once
  #pragma unroll
  for (int i = 0; i < 128*DIN/(8*256); ++i){
    int ch = t + i*256;
    int r = ch / (DIN/8), co = (ch % (DIN/8))*8;
    *(uint4*)(&As[r*AST + co]) = *(const uint4*)(V + (size_t)(node0+r)*DIN + co);
  }
  auto stageB = [&](int j, int buf){
    int chunk = j / KS, k0 = j % KS;
    int r = t>>2, ko = (t&3)*8;
    *(uint4*)(&Bs[buf][r][ko]) = *(const uint4*)(Wt + (size_t)(chunk*64 + r)*DIN + k0*32 + ko);
  };
  f32x4 sacc[4][2][4];
  #pragma unroll
  for (int cc=0;cc<4;++cc)
    #pragma unroll
    for (int rf=0;rf<2;++rf)
      #pragma unroll
      for (int cf=0;cf<4;++cf){ f32x4 z = {}; sacc[cc][rf][cf] = z; }
  stageB(0, 0);
  __syncthreads();                    // As + Bs[0] visible
  // ---- S phase: j = 0 .. 4*KS-1 ----
  #pragma unroll
  for (int j=0; j<4*KS; ++j){
    if (j+1 < NJ) stageB(j+1, (j+1)&1);
    const int k0 = j % KS, chunk = j / KS, buf = j & 1;
    bf16x8 a0 = *(const bf16x8*)(&As[(w*32 + lr)*AST + k0*32 + q*8]);
    bf16x8 a1 = *(const bf16x8*)(&As[(w*32 + 16 + lr)*AST + k0*32 + q*8]);
    #pragma unroll
    for (int cf=0;cf<4;++cf){
      bf16x8 b = *(const bf16x8*)(&Bs[buf][cf*16 + lr][q*8]);
      sacc[chunk][0][cf] = __builtin_amdgcn_mfma_f32_16x16x32_bf16(a0, b, sacc[chunk][0][cf], 0,0,0);
      sacc[chunk][1][cf] = __builtin_amdgcn_mfma_f32_16x16x32_bf16(a1, b, sacc[chunk][1][cf], 0,0,0);
    }
    __syncthreads();
  }
  // + bias
  #pragma unroll
  for (int cc=0;cc<4;++cc)
    #pragma unroll
    for (int cf=0;cf<4;++cf){
      float bv = cb[cc*64 + cf*16 + lr];
      #pragma unroll
      for (int rf=0;rf<2;++rf)
        #pragma unroll
        for (int i=0;i<4;++i) sacc[cc][rf][cf][i] += bv;
    }
  // ---- in-register softmax stats per row (rf,i): reduce over 16 frags + 16 lr lanes ----
  float m[2][4], iz[2][4];
  #pragma unroll
  for (int rf=0;rf<2;++rf){
    #pragma unroll
    for (int i=0;i<4;++i){
      float mx = -1e30f;
      #pragma unroll
      for (int cc=0;cc<4;++cc)
        #pragma unroll
        for (int cf=0;cf<4;++cf) mx = fmaxf(mx, sacc[cc][rf][cf][i]);
      #pragma unroll
      for (int off=1; off<16; off<<=1) mx = fmaxf(mx, __shfl_xor(mx, off));
      float zz = 0.f;
      #pragma unroll
      for (int cc=0;cc<4;++cc)
        #pragma unroll
        for (int cf=0;cf<4;++cf) zz += __expf(sacc[cc][rf][cf][i] - mx);
      #pragma unroll
      for (int off=1; off<16; off<<=1) zz += __shfl_xor(zz, off);
      m[rf][i] = mx; iz[rf][i] = 1.0f/zz;
    }
  }
  // ---- F phase: j = 4*KS .. NJ-1, consume each chunk at its last k-step ----
  const int bb = bid[node0];
  f32x4 facc[2][4];
  #pragma unroll
  for (int rf=0;rf<2;++rf)
    #pragma unroll
    for (int cf=0;cf<4;++cf){ f32x4 z = {}; facc[rf][cf] = z; }
  #pragma unroll
  for (int j=4*KS; j<NJ; ++j){
    if (j+1 < NJ) stageB(j+1, (j+1)&1);
    const int k0 = j % KS, chunk = j / KS, buf = j & 1;
    bf16x8 a0 = *(const bf16x8*)(&As[(w*32 + lr)*AST + k0*32 + q*8]);
    bf16x8 a1 = *(const bf16x8*)(&As[(w*32 + 16 + lr)*AST + k0*32 + q*8]);
    #pragma unroll
    for (int cf=0;cf<4;++cf){
      bf16x8 b = *(const bf16x8*)(&Bs[buf][cf*16 + lr][q*8]);
      facc[0][cf] = __builtin_amdgcn_mfma_f32_16x16x32_bf16(a0, b, facc[0][cf], 0,0,0);
      facc[1][cf] = __builtin_amdgcn_mfma_f32_16x16x32_bf16(a1, b, facc[1][cf], 0,0,0);
    }
    if (k0 == KS-1){
      const int sc = chunk - 4;       // S-chunk index matching these F cols
      #pragma unroll
      for (int cf=0;cf<4;++cf){
        float fb = cb[chunk*64 + cf*16 + lr];
        float cs = 0.f;
        #pragma unroll
        for (int rf=0;rf<2;++rf)
          #pragma unroll
          for (int i=0;i<4;++i){
            float p = __expf(sacc[sc][rf][cf][i] - m[rf][i]) * iz[rf][i];
            cs = fmaf(p, facc[rf][cf][i] + fb, cs);
          }
        cs += __shfl_xor(cs, 16);
        cs += __shfl_xor(cs, 32);
        if (q == 0) atomicAdd(&o[bb*256 + sc*64 + cf*16 + lr], cs);
      }
      #pragma unroll
      for (int rf=0;rf<2;++rf)
        #pragma unroll
        for (int cf=0;cf<4;++cf){ f32x4 z = {}; facc[rf][cf] = z; }
    }
    __syncthreads();
  }
}

// ---------------- fused attention (H=64 small layer)
template<int DIN, int H>
__global__ __launch_bounds__(256) void k_attnf(const u16* __restrict__ V, const u16* __restrict__ Wt,
        const float* __restrict__ cb, const int* __restrict__ bid, float* __restrict__ o){
  constexpr int CF  = H/64;
  constexpr int KS  = DIN/32;
  constexpr int AST = DIN + 8;
  constexpr int SST = H + 4;
  __shared__ u16 As[32*AST];
  __shared__ u16 Ssh[32*SST];
  __shared__ u16 Fsh[32*SST];
  __shared__ float mZ[2][32];
  const int t = threadIdx.x;
  const int node0 = blockIdx.x*32;
  const int lane = t & 63, w = t >> 6;
  const int lr = lane & 15, q = lane >> 4;
  #pragma unroll
  for (int i = 0; i < (32*DIN/8)/256; ++i){
    int ch = t + i*256;
    int r = ch / (DIN/8), co = (ch % (DIN/8))*8;
    *(uint4*)(&As[r*AST + co]) = *(const uint4*)(V + (size_t)(node0+r)*DIN + co);
  }
  __syncthreads();
  #pragma unroll
  for (int ph = 0; ph < 2; ++ph){
    f32x4 acc[2][CF];
    #pragma unroll
    for (int r=0;r<2;++r){
      #pragma unroll
      for (int c=0;c<CF;++c){ f32x4 z = {}; acc[r][c] = z; }
    }
    #pragma unroll
    for (int k=0;k<KS;++k){
      bf16x8 a0 = *(const bf16x8*)(&As[lr*AST + k*32 + q*8]);
      bf16x8 a1 = *(const bf16x8*)(&As[(16+lr)*AST + k*32 + q*8]);
      #pragma unroll
      for (int c=0;c<CF;++c){
        int col = ph*H + w*(16*CF) + c*16 + lr;
        bf16x8 b = *(const bf16x8*)(Wt + (size_t)col*DIN + k*32 + q*8);
        acc[0][c] = __builtin_amdgcn_mfma_f32_16x16x32_bf16(a0, b, acc[0][c], 0,0,0);
        acc[1][c] = __builtin_amdgcn_mfma_f32_16x16x32_bf16(a1, b, acc[1][c], 0,0,0);
      }
    }
    u16* dst = ph ? Fsh : Ssh;
    #pragma unroll
    for (int c=0;c<CF;++c){
      int colL = w*(16*CF) + c*16 + lr;
      float bias = cb[ph*H + colL];
      #pragma unroll
      for (int rf=0; rf<2; ++rf){
        #pragma unroll
        for (int i=0;i<4;++i){
          int row = rf*16 + q*4 + i;
          dst[row*SST + colL] = (u16)f2bf(acc[rf][c][i] + bias);
        }
      }
    }
    if (ph==0){
      __syncthreads();
      #pragma unroll
      for (int nn=0; nn<8; ++nn){
        int n = w*8 + nn;
        constexpr int VPL = H/64;
        float vals[VPL]; float mx = -1e30f;
        if constexpr (VPL == 4){
          uint2 uv = *(const uint2*)(&Ssh[n*SST + lane*4]);
          vals[0]=bflo(uv.x); vals[1]=bfhi(uv.x); vals[2]=bflo(uv.y); vals[3]=bfhi(uv.y);
          mx = fmaxf(fmaxf(vals[0],vals[1]), fmaxf(vals[2],vals[3]));
        } else {
          vals[0] = bflo((u32)Ssh[n*SST + lane]);
          mx = vals[0];
        }
        mx = wave_max(mx);
        float z = 0.f;
        #pragma unroll
        for (int i=0;i<VPL;++i) z += __expf(vals[i]-mx);
        z = wave_sum(z);
        if (lane==0){ mZ[0][n]=mx; mZ[1][n]=1.0f/z; }
      }
    }
  }
  __syncthreads();
  const int col = t % H;
  constexpr int NPER = 32*H/256;
  const int n0 = (t / H) * NPER;
  float acc2 = 0.f;
  #pragma unroll 8
  for (int n=n0; n<n0+NPER; ++n){
    float s = bflo((u32)Ssh[n*SST + col]);
    float f = bflo((u32)Fsh[n*SST + col]);
    acc2 = fmaf(__expf(s - mZ[0][n]) * mZ[1][n], f, acc2);
  }
  atomicAdd(&o[bid[node0]*H + col], acc2);
}

// ---------------- g update, parallel-K
template<int H, bool HASG>
__global__ __launch_bounds__(256) void k_gup2(const float* __restrict__ o, const float* __restrict__ gprev,
        const float* __restrict__ gw, const float* __restrict__ gb, float* __restrict__ gout){
  constexpr int KT = H + (HASG ? 256 : 0);
  constexpr int KPS = KT/8;
  __shared__ float vsh[KT];
  __shared__ float red[8][33];
  const int b = blockIdx.x;
  const int c = threadIdx.x & 31;
  const int s = threadIdx.x >> 5;
  const int col = blockIdx.y*32 + c;
  for (int k=threadIdx.x; k<KT; k+=256)
    vsh[k] = (k < H) ? o[b*H + k] : gprev[b*256 + (k - H)];
  __syncthreads();
  float acc = 0.f;
  const float* wp = gw + (size_t)(s*KPS)*256 + col;
  #pragma unroll 8
  for (int i=0;i<KPS;++i)
    acc = fmaf(vsh[s*KPS+i], wp[(size_t)i*256], acc);
  red[s][c] = acc;
  __syncthreads();
  if (s==0){
    float sum = 0.f;
    #pragma unroll
    for (int j=0;j<8;++j) sum += red[j][c];
    float gp = HASG ? gprev[b*256+col] : 0.f;
    gout[b*256+col] = gp + sum + gb[col];
  }
}

// ---------------- per-batch head bias, parallel-K
__global__ __launch_bounds__(256) void k_hb2(const float* __restrict__ g2, const float* __restrict__ o1w,
                                             const float* __restrict__ o1b, float* __restrict__ hb){
  __shared__ float vsh[256];
  __shared__ float red[8][33];
  const int b = blockIdx.x;
  const int c = threadIdx.x & 31;
  const int s = threadIdx.x >> 5;
  const int col = blockIdx.y*32 + c;
  vsh[threadIdx.x] = g2[b*256 + threadIdx.x];
  __syncthreads();
  float acc = 0.f;
  const float* wp = o1w + (size_t)(64 + s*32)*256 + col;
  #pragma unroll 8
  for (int i=0;i<32;++i)
    acc = fmaf(vsh[s*32+i], wp[(size_t)i*256], acc);
  red[s][c] = acc;
  __syncthreads();
  if (s==0){
    float sum = 0.f;
    #pragma unroll
    for (int j=0;j<8;++j) sum += red[j][c];
    hb[b*256+col] = sum + o1b[col];
  }
}

// ---------------- head layer 2 + pack
__global__ __launch_bounds__(256) void k_head2(const u16* __restrict__ z, const float* __restrict__ w,
        const float* __restrict__ bvec, const int* __restrict__ bid, const int* __restrict__ batches,
        float* __restrict__ out){
  __shared__ float zs[16][257];
  int t = threadIdx.x;
  int g0 = blockIdx.x*16;
  #pragma unroll
  for (int i=0;i<2;++i){
    int ch = t + i*256;
    int v = ch>>5, ko=(ch&31)*8;
    uint4 qv = *(const uint4*)(z + (size_t)(g0+v)*256 + ko);
    zs[v][ko+0]=bflo(qv.x); zs[v][ko+1]=bfhi(qv.x);
    zs[v][ko+2]=bflo(qv.y); zs[v][ko+3]=bfhi(qv.y);
    zs[v][ko+4]=bflo(qv.z); zs[v][ko+5]=bfhi(qv.z);
    zs[v][ko+6]=bflo(qv.w); zs[v][ko+7]=bfhi(qv.w);
  }
  __syncthreads();
  int v = t >> 4, c = t & 15;
  if (c < DIM_A){
    float acc = bvec[c];
    for (int k=0;k<256;++k) acc = fmaf(zs[v][k], w[k*DIM_A + c], acc);
    int node = g0 + v;
    int bb = bid[node];
    out[(size_t)bb*OUT_PER_B + (size_t)(node - batches[bb])*DIM_A + c] = acc;
  }
}

extern "C" void kernel_launch(void* const* d_in, const int* in_sizes, int n_in,
                              void* d_out, int out_size, void* d_ws, size_t ws_size,
                              hipStream_t stream){
  const float* x       = (const float*)d_in[0];
  const int*   ei      = (const int*)d_in[1];
  const int*   batches = (const int*)d_in[2];
  const float* conv1_w = (const float*)d_in[4];
  const float* conv1_b = (const float*)d_in[5];
  const float* conv2_w = (const float*)d_in[6];
  const float* conv2_b = (const float*)d_in[7];
  const float* g0_aw = (const float*)d_in[8];  const float* g0_ab = (const float*)d_in[9];
  const float* g0_fw = (const float*)d_in[10]; const float* g0_fb = (const float*)d_in[11];
  const float* g0_gw = (const float*)d_in[12]; const float* g0_gb = (const float*)d_in[13];
  const float* g1_aw = (const float*)d_in[14]; const float* g1_ab = (const float*)d_in[15];
  const float* g1_fw = (const float*)d_in[16]; const float* g1_fb = (const float*)d_in[17];
  const float* g1_gw = (const float*)d_in[18]; const float* g1_gb = (const float*)d_in[19];
  const float* g2_aw = (const float*)d_in[20]; const float* g2_ab = (const float*)d_in[21];
  const float* g2_fw = (const float*)d_in[22]; const float* g2_fb = (const float*)d_in[23];
  const float* g2_gw = (const float*)d_in[24]; const float* g2_gb = (const float*)d_in[25];
  const float* o1_w  = (const float*)d_in[26]; const float* o1_b  = (const float*)d_in[27];
  const float* o2_w  = (const float*)d_in[28]; const float* o2_b  = (const float*)d_in[29];
  float* out = (float*)d_out;

  char* W = (char*)d_ws;
  size_t off = 0;
  auto alloc = [&](size_t bytes)->void*{
    off = (off + 255) & ~(size_t)255;
    void* p = W + off; off += bytes; return p;
  };
  float* dis      = (float*)alloc(N_NODES*4);
  int*   cnt      = (int*)  alloc(N_NODES*4);
  int*   bid      = (int*)  alloc(N_NODES*4);
  int*   rowstart = (int*)  alloc(N_NODES*4);
  int*   cursor   = (int*)  alloc(N_NODES*4);
  int*   csr_src  = (int*)  alloc(N_EDGES*4);
  int*   bsum     = (int*)  alloc(256*4);
  int*   boff     = (int*)  alloc(256*4);
  float* o0       = (float*)alloc(NB*256*4);
  float* o1a      = (float*)alloc(NB*256*4);
  float* o2a      = (float*)alloc(NB*256*4);
  float* gv0      = (float*)alloc(NB*256*4);
  float* gv1      = (float*)alloc(NB*256*4);
  float* gv2      = (float*)alloc(NB*256*4);
  float* hb       = (float*)alloc(NB*256*4);
  float* cb0      = (float*)alloc(512*4);
  float* cb1      = (float*)alloc(512*4);
  float* cb2      = (float*)alloc(128*4);
  u16* conv1T = (u16*)alloc(32768*2);
  u16* Wt0    = (u16*)alloc(65536*2);
  u16* Wt1    = (u16*)alloc(131072*2);
  u16* conv2T = (u16*)alloc(16384*2);
  u16* Wt2    = (u16*)alloc(8192*2);
  u16* o1T    = (u16*)alloc(16384*2);
  u16* h1b    = (u16*)alloc((size_t)N_NODES*DIM_H1*2);   // 29.4 MB; reused as z
  u16* X      = (u16*)alloc((size_t)N_NODES*DIM_IN*2);   // 14.7 MB: xb; later hw2b | h2b
  u16* agg1b  = (u16*)alloc((size_t)N_NODES*DIM_IN*2);   // 14.7 MB
  u16* xb    = X;
  u16* hw2b  = X;
  u16* h2b   = X + (size_t)N_NODES*DIM_H2;
  u16* z     = h1b;

  // ---- init + CSR ----
  k_init <<<OUT_SZ/256, 256, 0, stream>>>(cnt, bid, batches, o0, out);
  k_deg  <<<N_EDGES/256, 256, 0, stream>>>(ei, cnt);
  k_scanA<<<N_NODES/256, 256, 0, stream>>>(cnt, bsum);
  k_scanB<<<1, 256, 0, stream>>>(bsum, boff);
  k_scanC<<<N_NODES/256, 256, 0, stream>>>(cnt, boff, rowstart, cursor, dis);
  k_place<<<N_EDGES/256, 256, 0, stream>>>(ei, cursor, csr_src);

  // ---- conversions / weight prep ----
  k_cvtx <<<N_NODES*DIM_IN/4/256, 256, 0, stream>>>(x, xb);
  k_prep <<<(270336+1152+255)/256, 256, 0, stream>>>(conv1_w, g0_aw, g0_fw, g1_aw, g1_fw, conv2_w,
            g2_aw, g2_fw, o1_w, g0_ab, g0_fb, g1_ab, g1_fb, g2_ab, g2_fb,
            conv1T, Wt0, Wt1, conv2T, Wt2, o1T, cb0, cb1, cb2);

  // ---- GCN1: aggregate then GEMM(+bias,relu) ----
  k_agg1b<<<N_NODES/4, 256, 0, stream>>>(xb, dis, rowstart, cnt, csr_src, agg1b);
  k_mm   <<<dim3(N_NODES/128, 4), 256, 0, stream>>>(agg1b, conv1T, conv1_b, nullptr, nullptr,
                                                    h1b, DIM_IN, DIM_H1, 4|1);
  // ---- fused attention 0 on xb ----
  k_attn4<128><<<N_NODES/128, 256, 0, stream>>>(xb, Wt0, cb0, bid, o0);
  k_gup2<256,false><<<dim3(NB,8), 256, 0, stream>>>(o0, nullptr, g0_gw, g0_gb, gv0);

  // ---- fused attention 1 on h1b ----
  k_attn4<256><<<N_NODES/128, 256, 0, stream>>>(h1b, Wt1, cb1, bid, o1a);
  k_gup2<256,true><<<dim3(NB,8), 256, 0, stream>>>(o1a, gv0, g1_gw, g1_gb, gv1);

  // ---- GCN2: GEMM then aggregate(+bias,relu) ----
  k_mm   <<<dim3(N_NODES/128, 1), 256, 0, stream>>>(h1b, conv2T, nullptr, nullptr, nullptr,
                                                    hw2b, DIM_H1, DIM_H2, 0);
  k_agg2b<<<N_NODES/4, 256, 0, stream>>>(hw2b, dis, rowstart, cnt, csr_src, conv2_b, h2b);

  // ---- fused attention 2 on h2b ----
  k_attnf<64,64><<<N_NODES/32, 256, 0, stream>>>(h2b, Wt2, cb2, bid, o2a);
  k_gup2<64,true><<<dim3(NB,8), 256, 0, stream>>>(o2a, gv1, g2_gw, g2_gb, gv2);

  // ---- head ----
  k_hb2  <<<dim3(NB,8), 256, 0, stream>>>(gv2, o1_w, o1_b, hb);
  k_mm   <<<dim3(N_NODES/128, 4), 256, 0, stream>>>(h2b, o1T, nullptr, hb, bid, z, DIM_H2, 256, 2|1);
  k_head2<<<N_NODES/16, 256, 0, stream>>>(z, o2_w, o2_b, bid, batches, out);

  (void)in_sizes; (void)n_in; (void)out_size; (void)ws_size;
}